// Round 1
// baseline (3000.898 us; speedup 1.0000x reference)
//
#include <hip/hip_runtime.h>
#include <math.h>

#define N_NODES 50000
#define DIN     128
#define DOUT    128
#define EPS_    1e-6f

// ---------------------------------------------------------------------------
// Kernel A: fused dense projection + ELU/ReLU + attention gate.
//   m = elu(mean @ Wm + bm) * exp(-v)
//   v = (relu(var @ Wv + bv) + eps) * exp(-v)^2
// Block = 256 threads = (128 cols x 2 rows). Rows staged in LDS (broadcast
// reads, conflict-free); W columns read coalesced from L1/L2 (64 KB, hot).
// ---------------------------------------------------------------------------
__global__ __launch_bounds__(256) void proj_kernel(
    const float* __restrict__ mean, const float* __restrict__ var,
    const float* __restrict__ Wm,   const float* __restrict__ bm,
    const float* __restrict__ Wv,   const float* __restrict__ bv,
    float* __restrict__ m_out, float* __restrict__ v_out)
{
    __shared__ float s_mean[2][DIN];
    __shared__ float s_var[2][DIN];

    const int tx  = threadIdx.x;
    const int c   = tx & 127;          // output column
    const int r   = tx >> 7;           // row within block (0..1)
    const int row = blockIdx.x * 2 + r;

    if (row < N_NODES) {
        s_mean[r][c] = mean[(size_t)row * DIN + c];
        s_var[r][c]  = var[(size_t)row * DIN + c];
    }
    __syncthreads();
    if (row >= N_NODES) return;

    float accm = bm[c];
    float accv = bv[c];
#pragma unroll 8
    for (int k = 0; k < DIN; ++k) {
        accm = fmaf(s_mean[r][k], Wm[k * DOUT + c], accm);
        accv = fmaf(s_var[r][k],  Wv[k * DOUT + c], accv);
    }

    float m = (accm > 0.0f) ? accm : (expf(accm) - 1.0f);   // ELU
    float v = ((accv > 0.0f) ? accv : 0.0f) + EPS_;          // ReLU + eps
    float att = expf(-v);
    m *= att;
    v *= att * att;

    m_out[(size_t)row * DOUT + c] = m;
    v_out[(size_t)row * DOUT + c] = v;
}

// ---------------------------------------------------------------------------
// Kernel B: COO SpMM scatter:  out_m[dst] += w0*m[src];  out_v[dst] += w1*v[src]
// 32 lanes per edge (128 floats = 32 x float4), 8 edges per 256-thread block.
// fp32 global atomics (device-scope by default on CDNA).
// ---------------------------------------------------------------------------
__global__ __launch_bounds__(256) void spmm_kernel(
    const float* __restrict__ m_in, const float* __restrict__ v_in,
    const float* __restrict__ w0,   const float* __restrict__ w1,
    const int*  __restrict__ src,   const int*  __restrict__ dst,
    float* __restrict__ out_m, float* __restrict__ out_v, int E)
{
    const int lane = threadIdx.x & 31;
    const int esub = threadIdx.x >> 5;
    const int e    = blockIdx.x * 8 + esub;
    if (e >= E) return;

    const int   s  = src[e];
    const int   d  = dst[e];
    const float a0 = w0[e];
    const float a1 = w1[e];

    const float4 mv = ((const float4*)(m_in + (size_t)s * DOUT))[lane];
    const float4 vv = ((const float4*)(v_in + (size_t)s * DOUT))[lane];

    float* om = out_m + (size_t)d * DOUT + lane * 4;
    float* ov = out_v + (size_t)d * DOUT + lane * 4;

    atomicAdd(om + 0, a0 * mv.x);
    atomicAdd(om + 1, a0 * mv.y);
    atomicAdd(om + 2, a0 * mv.z);
    atomicAdd(om + 3, a0 * mv.w);

    atomicAdd(ov + 0, a1 * vv.x);
    atomicAdd(ov + 1, a1 * vv.y);
    atomicAdd(ov + 2, a1 * vv.z);
    atomicAdd(ov + 3, a1 * vv.w);
}

// ---------------------------------------------------------------------------
extern "C" void kernel_launch(void* const* d_in, const int* in_sizes, int n_in,
                              void* d_out, int out_size, void* d_ws, size_t ws_size,
                              hipStream_t stream) {
    const float* mean = (const float*)d_in[0];
    const float* var  = (const float*)d_in[1];
    const float* Wm   = (const float*)d_in[2];
    const float* bm   = (const float*)d_in[3];
    const float* Wv   = (const float*)d_in[4];
    const float* bv   = (const float*)d_in[5];
    const float* a0   = (const float*)d_in[6];
    const float* a1   = (const float*)d_in[7];
    const int*   es   = (const int*)d_in[8];
    const int*   ed   = (const int*)d_in[9];
    const int    E    = in_sizes[6];

    float* m_buf = (float*)d_ws;                          // [N,128]
    float* v_buf = m_buf + (size_t)N_NODES * DOUT;        // [N,128]

    float* out_m = (float*)d_out;                         // [N,128]
    float* out_v = out_m + (size_t)N_NODES * DOUT;        // [N,128]

    // d_out is re-poisoned 0xAA before every timed launch — zero it.
    hipMemsetAsync(d_out, 0, (size_t)out_size * sizeof(float), stream);

    proj_kernel<<<(N_NODES + 1) / 2, 256, 0, stream>>>(
        mean, var, Wm, bm, Wv, bv, m_buf, v_buf);

    spmm_kernel<<<(E + 7) / 8, 256, 0, stream>>>(
        m_buf, v_buf, a0, a1, es, ed, out_m, out_v, E);
}

// Round 2
// 501.079 us; speedup vs baseline: 5.9889x; 5.9889x over previous
//
#include <hip/hip_runtime.h>
#include <hip/hip_bf16.h>
#include <math.h>

#define N_NODES 50000
#define DIN     128
#define DOUT    128
#define EPS_    1e-6f
#define NB_SCAN 196          // ceil(50000/256)

// ---------------------------------------------------------------------------
// Kernel 1: fused dense projection + ELU/ReLU + attention gate, bf16 output.
// Register-blocked: block=256 threads, tile M=16 rows; thread = 4 rows x 2
// cols x 2 matrices (16 fp32 accumulators). Row loads are wave-uniform
// (broadcast via L1); W loads coalesced float2. No LDS, no syncthreads.
// ---------------------------------------------------------------------------
__global__ __launch_bounds__(256) void proj_kernel(
    const float* __restrict__ mean, const float* __restrict__ var,
    const float* __restrict__ Wm,   const float* __restrict__ bm,
    const float* __restrict__ Wv,   const float* __restrict__ bv,
    __hip_bfloat16* __restrict__ m_bf, __hip_bfloat16* __restrict__ v_bf)
{
    const int t    = threadIdx.x;
    const int cq   = t & 63;               // 64 col-pairs -> 128 cols
    const int rq   = t >> 6;               // 4 row-quads (wave-uniform)
    const int c0   = cq * 2;
    const int row0 = blockIdx.x * 16 + rq * 4;

    float accm[4][2], accv[4][2];
    const float bm0 = bm[c0], bm1 = bm[c0 + 1];
    const float bv0 = bv[c0], bv1 = bv[c0 + 1];
#pragma unroll
    for (int i = 0; i < 4; ++i) {
        accm[i][0] = bm0; accm[i][1] = bm1;
        accv[i][0] = bv0; accv[i][1] = bv1;
    }

    const float* mrow = mean + (size_t)row0 * DIN;
    const float* vrow = var  + (size_t)row0 * DIN;

#pragma unroll 4
    for (int k = 0; k < DIN; ++k) {
        const float2 wm = *(const float2*)(Wm + k * DOUT + c0);
        const float2 wv = *(const float2*)(Wv + k * DOUT + c0);
#pragma unroll
        for (int i = 0; i < 4; ++i) {
            const float am = mrow[i * DIN + k];
            const float av = vrow[i * DIN + k];
            accm[i][0] = fmaf(am, wm.x, accm[i][0]);
            accm[i][1] = fmaf(am, wm.y, accm[i][1]);
            accv[i][0] = fmaf(av, wv.x, accv[i][0]);
            accv[i][1] = fmaf(av, wv.y, accv[i][1]);
        }
    }

#pragma unroll
    for (int i = 0; i < 4; ++i) {
        const int row = row0 + i;
        float mo[2], vo[2];
#pragma unroll
        for (int j = 0; j < 2; ++j) {
            float m = accm[i][j];
            m = (m > 0.0f) ? m : (expf(m) - 1.0f);           // ELU
            float v = accv[i][j];
            v = ((v > 0.0f) ? v : 0.0f) + EPS_;              // ReLU + eps
            const float att = expf(-v);
            mo[j] = m * att;
            vo[j] = v * att * att;
        }
        __hip_bfloat162 hm, hv;
        hm.x = __float2bfloat16(mo[0]); hm.y = __float2bfloat16(mo[1]);
        hv.x = __float2bfloat16(vo[0]); hv.y = __float2bfloat16(vo[1]);
        *(__hip_bfloat162*)(m_bf + (size_t)row * DOUT + c0) = hm;
        *(__hip_bfloat162*)(v_bf + (size_t)row * DOUT + c0) = hv;
    }
}

// ---------------------------------------------------------------------------
// Kernel 2: histogram of dst  (counts accumulated into `cursor`)
// ---------------------------------------------------------------------------
__global__ __launch_bounds__(256) void count_kernel(
    const int* __restrict__ dst, int* __restrict__ cursor, int E)
{
    const int e = blockIdx.x * 256 + threadIdx.x;
    if (e < E) atomicAdd(&cursor[dst[e]], 1);
}

// ---------------------------------------------------------------------------
// Kernel 3a: per-256-chunk sums of counts
// ---------------------------------------------------------------------------
__global__ __launch_bounds__(256) void scan_bsum_kernel(
    const int* __restrict__ counts, int* __restrict__ bsum)
{
    __shared__ int s[256];
    const int t = threadIdx.x;
    const int i = blockIdx.x * 256 + t;
    s[t] = (i < N_NODES) ? counts[i] : 0;
    __syncthreads();
    for (int off = 128; off > 0; off >>= 1) {
        if (t < off) s[t] += s[t + off];
        __syncthreads();
    }
    if (t == 0) bsum[blockIdx.x] = s[0];
}

// ---------------------------------------------------------------------------
// Kernel 3b: exclusive scan of the 196 block sums (single block)
// ---------------------------------------------------------------------------
__global__ __launch_bounds__(256) void scan_offsets_kernel(int* __restrict__ bsum)
{
    __shared__ int s[256];
    const int t = threadIdx.x;
    const int x = (t < NB_SCAN) ? bsum[t] : 0;
    s[t] = x;
    __syncthreads();
    for (int off = 1; off < 256; off <<= 1) {
        const int v = (t >= off) ? s[t - off] : 0;
        __syncthreads();
        s[t] += v;
        __syncthreads();
    }
    if (t < NB_SCAN) bsum[t] = s[t] - x;   // exclusive
}

// ---------------------------------------------------------------------------
// Kernel 3c: final scan — node_start[i] and cursor[i] = global exclusive sum
// ---------------------------------------------------------------------------
__global__ __launch_bounds__(256) void scan_final_kernel(
    const int* __restrict__ bsum, int* __restrict__ cursor,
    int* __restrict__ node_start, int E)
{
    __shared__ int s[256];
    const int t = threadIdx.x;
    const int i = blockIdx.x * 256 + t;
    const int x = (i < N_NODES) ? cursor[i] : 0;
    s[t] = x;
    __syncthreads();
    for (int off = 1; off < 256; off <<= 1) {
        const int v = (t >= off) ? s[t - off] : 0;
        __syncthreads();
        s[t] += v;
        __syncthreads();
    }
    const int start = bsum[blockIdx.x] + (s[t] - x);
    if (i < N_NODES) {
        node_start[i] = start;
        cursor[i]     = start;
    }
    if (i == 0) node_start[N_NODES] = E;
}

// ---------------------------------------------------------------------------
// Kernel 4: scatter packed edge records to dst-sorted order
// ---------------------------------------------------------------------------
__global__ __launch_bounds__(256) void scatter_kernel(
    const int* __restrict__ src, const int* __restrict__ dst,
    const float* __restrict__ w0, const float* __restrict__ w1,
    int* __restrict__ cursor, int4* __restrict__ edges, int E)
{
    const int e = blockIdx.x * 256 + threadIdx.x;
    if (e >= E) return;
    const int d   = dst[e];
    const int pos = atomicAdd(&cursor[d], 1);
    edges[pos] = make_int4(src[e], __float_as_int(w0[e]), __float_as_int(w1[e]), 0);
}

// ---------------------------------------------------------------------------
// Kernel 5: gather aggregation — one 64-lane wave per dst node, 2 features
// per lane (bf16x2 loads). Zero atomics; fully overwrites d_out.
// ---------------------------------------------------------------------------
__global__ __launch_bounds__(256) void agg_kernel(
    const unsigned short* __restrict__ m_bf, const unsigned short* __restrict__ v_bf,
    const int4* __restrict__ edges, const int* __restrict__ node_start,
    float* __restrict__ out_m, float* __restrict__ out_v)
{
    const int node = blockIdx.x * 4 + (threadIdx.x >> 6);
    const int lane = threadIdx.x & 63;
    if (node >= N_NODES) return;

    const int j0 = node_start[node];
    const int j1 = node_start[node + 1];

    float m0 = 0.f, m1 = 0.f, v0 = 0.f, v1 = 0.f;
    for (int j = j0; j < j1; ++j) {
        const int4 ed = edges[j];
        const float a0 = __int_as_float(ed.y);
        const float a1 = __int_as_float(ed.z);
        const unsigned pm = *(const unsigned*)(m_bf + (size_t)ed.x * DOUT + lane * 2);
        const unsigned pv = *(const unsigned*)(v_bf + (size_t)ed.x * DOUT + lane * 2);
        const float mm0 = __uint_as_float(pm << 16);
        const float mm1 = __uint_as_float(pm & 0xffff0000u);
        const float vv0 = __uint_as_float(pv << 16);
        const float vv1 = __uint_as_float(pv & 0xffff0000u);
        m0 = fmaf(a0, mm0, m0); m1 = fmaf(a0, mm1, m1);
        v0 = fmaf(a1, vv0, v0); v1 = fmaf(a1, vv1, v1);
    }
    *(float2*)(out_m + (size_t)node * DOUT + lane * 2) = make_float2(m0, m1);
    *(float2*)(out_v + (size_t)node * DOUT + lane * 2) = make_float2(v0, v1);
}

// ---------------------------------------------------------------------------
extern "C" void kernel_launch(void* const* d_in, const int* in_sizes, int n_in,
                              void* d_out, int out_size, void* d_ws, size_t ws_size,
                              hipStream_t stream) {
    const float* mean = (const float*)d_in[0];
    const float* var  = (const float*)d_in[1];
    const float* Wm   = (const float*)d_in[2];
    const float* bm   = (const float*)d_in[3];
    const float* Wv   = (const float*)d_in[4];
    const float* bv   = (const float*)d_in[5];
    const float* a0   = (const float*)d_in[6];
    const float* a1   = (const float*)d_in[7];
    const int*   es   = (const int*)d_in[8];
    const int*   ed   = (const int*)d_in[9];
    const int    E    = in_sizes[6];

    // Workspace layout (all 16B-aligned):
    //   m_bf [N,128] bf16 : 12.8 MB
    //   v_bf [N,128] bf16 : 12.8 MB
    //   edges [E] int4    : 12.8 MB
    //   node_start [N+1]  : 200 KB
    //   cursor [N]        : 200 KB
    //   bsum [256]        : 1 KB     (total ~38.8 MB)
    char* ws = (char*)d_ws;
    __hip_bfloat16* m_bf   = (__hip_bfloat16*)ws;
    __hip_bfloat16* v_bf   = (__hip_bfloat16*)(ws + 12800000);
    int4*  edges           = (int4*)(ws + 25600000);
    int*   node_start      = (int*) (ws + 38400000);
    int*   cursor          = (int*) (ws + 38400000 + 200016);
    int*   bsum            = (int*) (ws + 38400000 + 200016 + 200000);

    float* out_m = (float*)d_out;
    float* out_v = out_m + (size_t)N_NODES * DOUT;

    // counts must start at zero (ws is poisoned 0xAA each call)
    hipMemsetAsync(cursor, 0, (size_t)N_NODES * sizeof(int), stream);

    proj_kernel<<<N_NODES / 16, 256, 0, stream>>>(
        mean, var, Wm, bm, Wv, bv, m_bf, v_bf);

    const int eb = (E + 255) / 256;
    count_kernel       <<<eb,      256, 0, stream>>>(ed, cursor, E);
    scan_bsum_kernel   <<<NB_SCAN, 256, 0, stream>>>(cursor, bsum);
    scan_offsets_kernel<<<1,       256, 0, stream>>>(bsum);
    scan_final_kernel  <<<NB_SCAN, 256, 0, stream>>>(bsum, cursor, node_start, E);
    scatter_kernel     <<<eb,      256, 0, stream>>>(es, ed, a0, a1, cursor, edges, E);

    agg_kernel<<<(N_NODES + 3) / 4, 256, 0, stream>>>(
        (const unsigned short*)m_bf, (const unsigned short*)v_bf,
        edges, node_start, out_m, out_v);
}

// Round 3
// 324.289 us; speedup vs baseline: 9.2538x; 1.5452x over previous
//
#include <hip/hip_runtime.h>
#include <hip/hip_bf16.h>
#include <math.h>

#define N_NODES 50000
#define DIN     128
#define DOUT    128
#define EPS_    1e-6f
#define NB_SCAN 196          // ceil(50000/256)
#define N_WAVES 3125         // N_NODES / 16 rows per wave (exact)

typedef __attribute__((ext_vector_type(8))) short  bf16x8;
typedef __attribute__((ext_vector_type(4))) float  f32x4;
typedef unsigned short ushort_t;

// round-to-nearest-even fp32 -> bf16 (finite inputs)
__device__ __forceinline__ ushort_t f2bf(float f) {
    unsigned u = __float_as_uint(f);
    return (ushort_t)((u + 0x7fffu + ((u >> 16) & 1u)) >> 16);
}
__device__ __forceinline__ float bf2f(unsigned short h) {
    return __uint_as_float(((unsigned)h) << 16);
}

// ---------------------------------------------------------------------------
// Kernel 0: pre-pack Wm/Wv (fp32 row-major [k][n]) into bf16 B-fragment order
// for mfma_f32_16x16x32_bf16:  B[k = quad*8+j][n = lane&15], fragment chunk
// index (ct,kk) with ct=n>>4, kk=k>>5. Lane reads 16B contiguous at
// ((ct*4+kk)*64 + lane)*8 ushorts.
// ---------------------------------------------------------------------------
__global__ __launch_bounds__(256) void prep_w_kernel(
    const float* __restrict__ Wm, const float* __restrict__ Wv,
    ushort_t* __restrict__ fm, ushort_t* __restrict__ fv)
{
    const int gid = blockIdx.x * 256 + threadIdx.x;   // 16384 threads
    const int k = gid >> 7, n = gid & 127;
    const int ct = n >> 4, kk = k >> 5, quad = (k >> 3) & 3, j = k & 7;
    const int idx = ((ct * 4 + kk) * 64 + quad * 16 + (n & 15)) * 8 + j;
    fm[idx] = f2bf(Wm[gid]);
    fv[idx] = f2bf(Wv[gid]);
}

// ---------------------------------------------------------------------------
// Kernel 1: MFMA projection + ELU/ReLU + gate, bf16 out.
// One wave = 16 rows x 128 cols, both matrices. K=128 in 4 steps of 32.
// A-frag: row = lane&15, k = kk*32 + (lane>>4)*8 + j  (global fp32 -> bf16).
// C/D:    col = lane&15, row = (lane>>4)*4 + reg      [m89-verified].
// ---------------------------------------------------------------------------
__global__ __launch_bounds__(256) void proj_mfma_kernel(
    const float* __restrict__ mean, const float* __restrict__ var,
    const float* __restrict__ bm,   const float* __restrict__ bv,
    const ushort_t* __restrict__ wfm, const ushort_t* __restrict__ wfv,
    ushort_t* __restrict__ m_bf, ushort_t* __restrict__ v_bf)
{
    const int wave = blockIdx.x * 4 + (threadIdx.x >> 6);
    if (wave >= N_WAVES) return;
    const int lane = threadIdx.x & 63;
    const int row0 = wave * 16;
    const int kq   = lane >> 4;             // 0..3
    const int arow = row0 + (lane & 15);

    f32x4 accm[8], accv[8];
#pragma unroll
    for (int ct = 0; ct < 8; ++ct) {
        accm[ct] = (f32x4){0.f, 0.f, 0.f, 0.f};
        accv[ct] = (f32x4){0.f, 0.f, 0.f, 0.f};
    }

    const float* mrow = mean + (size_t)arow * DIN;
    const float* vrow = var  + (size_t)arow * DIN;

#pragma unroll
    for (int kk = 0; kk < 4; ++kk) {
        const int kb = kk * 32 + kq * 8;
        const float4 am0 = *(const float4*)(mrow + kb);
        const float4 am1 = *(const float4*)(mrow + kb + 4);
        const float4 av0 = *(const float4*)(vrow + kb);
        const float4 av1 = *(const float4*)(vrow + kb + 4);
        bf16x8 a_m, a_v;
        a_m[0]=f2bf(am0.x); a_m[1]=f2bf(am0.y); a_m[2]=f2bf(am0.z); a_m[3]=f2bf(am0.w);
        a_m[4]=f2bf(am1.x); a_m[5]=f2bf(am1.y); a_m[6]=f2bf(am1.z); a_m[7]=f2bf(am1.w);
        a_v[0]=f2bf(av0.x); a_v[1]=f2bf(av0.y); a_v[2]=f2bf(av0.z); a_v[3]=f2bf(av0.w);
        a_v[4]=f2bf(av1.x); a_v[5]=f2bf(av1.y); a_v[6]=f2bf(av1.z); a_v[7]=f2bf(av1.w);

#pragma unroll
        for (int ct = 0; ct < 8; ++ct) {
            const bf16x8 b_m = *(const bf16x8*)(wfm + ((size_t)(ct * 4 + kk) * 64 + lane) * 8);
            const bf16x8 b_v = *(const bf16x8*)(wfv + ((size_t)(ct * 4 + kk) * 64 + lane) * 8);
            accm[ct] = __builtin_amdgcn_mfma_f32_16x16x32_bf16(a_m, b_m, accm[ct], 0, 0, 0);
            accv[ct] = __builtin_amdgcn_mfma_f32_16x16x32_bf16(a_v, b_v, accv[ct], 0, 0, 0);
        }
    }

    // epilogue: bias + ELU/ReLU + gate, store bf16
#pragma unroll
    for (int ct = 0; ct < 8; ++ct) {
        const int col = ct * 16 + (lane & 15);
        const float bmc = bm[col];
        const float bvc = bv[col];
#pragma unroll
        for (int r = 0; r < 4; ++r) {
            const int row = row0 + kq * 4 + r;
            float m = accm[ct][r] + bmc;
            m = (m > 0.0f) ? m : (expf(m) - 1.0f);           // ELU
            float v = accv[ct][r] + bvc;
            v = ((v > 0.0f) ? v : 0.0f) + EPS_;              // ReLU + eps
            const float att = expf(-v);
            m_bf[(size_t)row * DOUT + col] = f2bf(m * att);
            v_bf[(size_t)row * DOUT + col] = f2bf(v * att * att);
        }
    }
}

// ---------------------------------------------------------------------------
// Kernel 2: histogram of dst
// ---------------------------------------------------------------------------
__global__ __launch_bounds__(256) void count_kernel(
    const int* __restrict__ dst, int* __restrict__ cursor, int E)
{
    const int e = blockIdx.x * 256 + threadIdx.x;
    if (e < E) atomicAdd(&cursor[dst[e]], 1);
}

// ---------------------------------------------------------------------------
// Kernel 3a: per-256-chunk sums of counts
// ---------------------------------------------------------------------------
__global__ __launch_bounds__(256) void scan_bsum_kernel(
    const int* __restrict__ counts, int* __restrict__ bsum)
{
    __shared__ int s[256];
    const int t = threadIdx.x;
    const int i = blockIdx.x * 256 + t;
    s[t] = (i < N_NODES) ? counts[i] : 0;
    __syncthreads();
    for (int off = 128; off > 0; off >>= 1) {
        if (t < off) s[t] += s[t + off];
        __syncthreads();
    }
    if (t == 0) bsum[blockIdx.x] = s[0];
}

// ---------------------------------------------------------------------------
// Kernel 3b: exclusive scan of the 196 block sums (single block)
// ---------------------------------------------------------------------------
__global__ __launch_bounds__(256) void scan_offsets_kernel(int* __restrict__ bsum)
{
    __shared__ int s[256];
    const int t = threadIdx.x;
    const int x = (t < NB_SCAN) ? bsum[t] : 0;
    s[t] = x;
    __syncthreads();
    for (int off = 1; off < 256; off <<= 1) {
        const int v = (t >= off) ? s[t - off] : 0;
        __syncthreads();
        s[t] += v;
        __syncthreads();
    }
    if (t < NB_SCAN) bsum[t] = s[t] - x;   // exclusive
}

// ---------------------------------------------------------------------------
// Kernel 3c: final scan — node_start[i] and cursor[i] = global exclusive sum
// ---------------------------------------------------------------------------
__global__ __launch_bounds__(256) void scan_final_kernel(
    const int* __restrict__ bsum, int* __restrict__ cursor,
    int* __restrict__ node_start, int E)
{
    __shared__ int s[256];
    const int t = threadIdx.x;
    const int i = blockIdx.x * 256 + t;
    const int x = (i < N_NODES) ? cursor[i] : 0;
    s[t] = x;
    __syncthreads();
    for (int off = 1; off < 256; off <<= 1) {
        const int v = (t >= off) ? s[t - off] : 0;
        __syncthreads();
        s[t] += v;
        __syncthreads();
    }
    const int start = bsum[blockIdx.x] + (s[t] - x);
    if (i < N_NODES) {
        node_start[i] = start;
        cursor[i]     = start;
    }
    if (i == 0) node_start[N_NODES] = E;
}

// ---------------------------------------------------------------------------
// Kernel 4: scatter packed edge records to dst-sorted order
// ---------------------------------------------------------------------------
__global__ __launch_bounds__(256) void scatter_kernel(
    const int* __restrict__ src, const int* __restrict__ dst,
    const float* __restrict__ w0, const float* __restrict__ w1,
    int* __restrict__ cursor, int4* __restrict__ edges, int E)
{
    const int e = blockIdx.x * 256 + threadIdx.x;
    if (e >= E) return;
    const int d   = dst[e];
    const int pos = atomicAdd(&cursor[d], 1);
    edges[pos] = make_int4(src[e], __float_as_int(w0[e]), __float_as_int(w1[e]), 0);
}

// ---------------------------------------------------------------------------
// Kernel 5: gather aggregation — one 64-lane wave per dst node, 2 features
// per lane. Edge record prefetched one iteration ahead. Zero atomics.
// ---------------------------------------------------------------------------
__global__ __launch_bounds__(256) void agg_kernel(
    const ushort_t* __restrict__ m_bf, const ushort_t* __restrict__ v_bf,
    const int4* __restrict__ edges, const int* __restrict__ node_start,
    float* __restrict__ out_m, float* __restrict__ out_v)
{
    const int node = blockIdx.x * 4 + (threadIdx.x >> 6);
    const int lane = threadIdx.x & 63;
    if (node >= N_NODES) return;

    const int j0 = node_start[node];
    const int j1 = node_start[node + 1];

    float m0 = 0.f, m1 = 0.f, v0 = 0.f, v1 = 0.f;
    if (j0 < j1) {
        int4 ed = edges[j0];
        for (int j = j0; j < j1; ++j) {
            const int4 cur = ed;
            if (j + 1 < j1) ed = edges[j + 1];    // prefetch next record
            const float a0 = __int_as_float(cur.y);
            const float a1 = __int_as_float(cur.z);
            const unsigned pm = *(const unsigned*)(m_bf + (size_t)cur.x * DOUT + lane * 2);
            const unsigned pv = *(const unsigned*)(v_bf + (size_t)cur.x * DOUT + lane * 2);
            m0 = fmaf(a0, __uint_as_float(pm << 16),        m0);
            m1 = fmaf(a0, __uint_as_float(pm & 0xffff0000u), m1);
            v0 = fmaf(a1, __uint_as_float(pv << 16),        v0);
            v1 = fmaf(a1, __uint_as_float(pv & 0xffff0000u), v1);
        }
    }
    *(float2*)(out_m + (size_t)node * DOUT + lane * 2) = make_float2(m0, m1);
    *(float2*)(out_v + (size_t)node * DOUT + lane * 2) = make_float2(v0, v1);
}

// ---------------------------------------------------------------------------
extern "C" void kernel_launch(void* const* d_in, const int* in_sizes, int n_in,
                              void* d_out, int out_size, void* d_ws, size_t ws_size,
                              hipStream_t stream) {
    const float* mean = (const float*)d_in[0];
    const float* var  = (const float*)d_in[1];
    const float* Wm   = (const float*)d_in[2];
    const float* bm   = (const float*)d_in[3];
    const float* Wv   = (const float*)d_in[4];
    const float* bv   = (const float*)d_in[5];
    const float* a0   = (const float*)d_in[6];
    const float* a1   = (const float*)d_in[7];
    const int*   es   = (const int*)d_in[8];
    const int*   ed   = (const int*)d_in[9];
    const int    E    = in_sizes[6];

    // Workspace layout:
    //   m_bf [N,128] bf16   12.8 MB
    //   v_bf [N,128] bf16   12.8 MB
    //   edges [E] int4      12.8 MB
    //   node_start [N+1]    200 KB
    //   cursor [N]          200 KB
    //   bsum [256]          1 KB
    //   wfm/wfv frag bf16   64 KB
    char* ws = (char*)d_ws;
    ushort_t* m_bf      = (ushort_t*)ws;
    ushort_t* v_bf      = (ushort_t*)(ws + 12800000);
    int4*  edges        = (int4*)(ws + 25600000);
    int*   node_start   = (int*) (ws + 38400000);
    int*   cursor       = (int*) (ws + 38400000 + 200016);
    int*   bsum         = (int*) (ws + 38400000 + 200016 + 200000);
    ushort_t* wfm       = (ushort_t*)(ws + 38400000 + 200016 + 200000 + 1024);
    ushort_t* wfv       = wfm + 16384;

    float* out_m = (float*)d_out;
    float* out_v = out_m + (size_t)N_NODES * DOUT;

    // counts must start at zero (ws is poisoned 0xAA each call)
    hipMemsetAsync(cursor, 0, (size_t)N_NODES * sizeof(int), stream);

    prep_w_kernel<<<64, 256, 0, stream>>>(Wm, Wv, wfm, wfv);

    proj_mfma_kernel<<<(N_WAVES + 3) / 4, 256, 0, stream>>>(
        mean, var, bm, bv, wfm, wfv, m_bf, v_bf);

    const int eb = (E + 255) / 256;
    count_kernel       <<<eb,      256, 0, stream>>>(ed, cursor, E);
    scan_bsum_kernel   <<<NB_SCAN, 256, 0, stream>>>(cursor, bsum);
    scan_offsets_kernel<<<1,       256, 0, stream>>>(bsum);
    scan_final_kernel  <<<NB_SCAN, 256, 0, stream>>>(bsum, cursor, node_start, E);
    scatter_kernel     <<<eb,      256, 0, stream>>>(es, ed, a0, a1, cursor, edges, E);

    agg_kernel<<<(N_NODES + 3) / 4, 256, 0, stream>>>(
        m_bf, v_bf, edges, node_start, out_m, out_v);
}

// Round 4
// 303.040 us; speedup vs baseline: 9.9027x; 1.0701x over previous
//
#include <hip/hip_runtime.h>
#include <hip/hip_bf16.h>
#include <math.h>

#define N_NODES 50000
#define DIN     128
#define DOUT    128
#define EPS_    1e-6f
#define NB_SCAN 196          // ceil(50000/256)
#define N_WAVES 3125         // N_NODES / 16 rows per wave (exact)

typedef __attribute__((ext_vector_type(8))) short  bf16x8;
typedef __attribute__((ext_vector_type(4))) float  f32x4;
typedef unsigned short ushort_t;

// round-to-nearest-even fp32 -> bf16 (finite inputs)
__device__ __forceinline__ ushort_t f2bf(float f) {
    unsigned u = __float_as_uint(f);
    return (ushort_t)((u + 0x7fffu + ((u >> 16) & 1u)) >> 16);
}

// ---------------------------------------------------------------------------
// Kernel 0: pre-pack Wm/Wv (fp32 row-major [k][n]) into bf16 B-fragment order
// for mfma_f32_16x16x32_bf16 (see R3 notes).
// ---------------------------------------------------------------------------
__global__ __launch_bounds__(256) void prep_w_kernel(
    const float* __restrict__ Wm, const float* __restrict__ Wv,
    ushort_t* __restrict__ fm, ushort_t* __restrict__ fv)
{
    const int gid = blockIdx.x * 256 + threadIdx.x;   // 16384 threads
    const int k = gid >> 7, n = gid & 127;
    const int ct = n >> 4, kk = k >> 5, quad = (k >> 3) & 3, j = k & 7;
    const int idx = ((ct * 4 + kk) * 64 + quad * 16 + (n & 15)) * 8 + j;
    fm[idx] = f2bf(Wm[gid]);
    fv[idx] = f2bf(Wv[gid]);
}

// ---------------------------------------------------------------------------
// Kernel 1: MFMA projection + ELU/ReLU + gate. Writes the COMBINED bf16
// buffer mv[row][256]: pair p stores {m_2p, m_2p+1, v_2p, v_2p+1} so the
// agg kernel fetches both matrices with one dwordx2 per lane.
// ---------------------------------------------------------------------------
__global__ __launch_bounds__(256) void proj_mfma_kernel(
    const float* __restrict__ mean, const float* __restrict__ var,
    const float* __restrict__ bm,   const float* __restrict__ bv,
    const ushort_t* __restrict__ wfm, const ushort_t* __restrict__ wfv,
    ushort_t* __restrict__ mv)
{
    const int wave = blockIdx.x * 4 + (threadIdx.x >> 6);
    if (wave >= N_WAVES) return;
    const int lane = threadIdx.x & 63;
    const int row0 = wave * 16;
    const int kq   = lane >> 4;             // 0..3
    const int arow = row0 + (lane & 15);

    f32x4 accm[8], accv[8];
#pragma unroll
    for (int ct = 0; ct < 8; ++ct) {
        accm[ct] = (f32x4){0.f, 0.f, 0.f, 0.f};
        accv[ct] = (f32x4){0.f, 0.f, 0.f, 0.f};
    }

    const float* mrow = mean + (size_t)arow * DIN;
    const float* vrow = var  + (size_t)arow * DIN;

#pragma unroll
    for (int kk = 0; kk < 4; ++kk) {
        const int kb = kk * 32 + kq * 8;
        const float4 am0 = *(const float4*)(mrow + kb);
        const float4 am1 = *(const float4*)(mrow + kb + 4);
        const float4 av0 = *(const float4*)(vrow + kb);
        const float4 av1 = *(const float4*)(vrow + kb + 4);
        bf16x8 a_m, a_v;
        a_m[0]=f2bf(am0.x); a_m[1]=f2bf(am0.y); a_m[2]=f2bf(am0.z); a_m[3]=f2bf(am0.w);
        a_m[4]=f2bf(am1.x); a_m[5]=f2bf(am1.y); a_m[6]=f2bf(am1.z); a_m[7]=f2bf(am1.w);
        a_v[0]=f2bf(av0.x); a_v[1]=f2bf(av0.y); a_v[2]=f2bf(av0.z); a_v[3]=f2bf(av0.w);
        a_v[4]=f2bf(av1.x); a_v[5]=f2bf(av1.y); a_v[6]=f2bf(av1.z); a_v[7]=f2bf(av1.w);

#pragma unroll
        for (int ct = 0; ct < 8; ++ct) {
            const bf16x8 b_m = *(const bf16x8*)(wfm + ((size_t)(ct * 4 + kk) * 64 + lane) * 8);
            const bf16x8 b_v = *(const bf16x8*)(wfv + ((size_t)(ct * 4 + kk) * 64 + lane) * 8);
            accm[ct] = __builtin_amdgcn_mfma_f32_16x16x32_bf16(a_m, b_m, accm[ct], 0, 0, 0);
            accv[ct] = __builtin_amdgcn_mfma_f32_16x16x32_bf16(a_v, b_v, accv[ct], 0, 0, 0);
        }
    }

    // epilogue: bias + ELU/ReLU + gate, store into interleaved mv buffer
#pragma unroll
    for (int ct = 0; ct < 8; ++ct) {
        const int col = ct * 16 + (lane & 15);
        const float bmc = bm[col];
        const float bvc = bv[col];
        const int pbase = (col >> 1) * 4 + (col & 1);   // pair-interleave offset
#pragma unroll
        for (int r = 0; r < 4; ++r) {
            const int row = row0 + kq * 4 + r;
            float m = accm[ct][r] + bmc;
            m = (m > 0.0f) ? m : (expf(m) - 1.0f);           // ELU
            float v = accv[ct][r] + bvc;
            v = ((v > 0.0f) ? v : 0.0f) + EPS_;              // ReLU + eps
            const float att = expf(-v);
            ushort_t* rowp = mv + (size_t)row * 256;
            rowp[pbase]     = f2bf(m * att);
            rowp[pbase + 2] = f2bf(v * att * att);
        }
    }
}

// ---------------------------------------------------------------------------
// Kernel 2: histogram of dst
// ---------------------------------------------------------------------------
__global__ __launch_bounds__(256) void count_kernel(
    const int* __restrict__ dst, int* __restrict__ cursor, int E)
{
    const int e = blockIdx.x * 256 + threadIdx.x;
    if (e < E) atomicAdd(&cursor[dst[e]], 1);
}

// ---------------------------------------------------------------------------
// Kernel 3a: per-256-chunk sums of counts
// ---------------------------------------------------------------------------
__global__ __launch_bounds__(256) void scan_bsum_kernel(
    const int* __restrict__ counts, int* __restrict__ bsum)
{
    __shared__ int s[256];
    const int t = threadIdx.x;
    const int i = blockIdx.x * 256 + t;
    s[t] = (i < N_NODES) ? counts[i] : 0;
    __syncthreads();
    for (int off = 128; off > 0; off >>= 1) {
        if (t < off) s[t] += s[t + off];
        __syncthreads();
    }
    if (t == 0) bsum[blockIdx.x] = s[0];
}

// ---------------------------------------------------------------------------
// Kernel 3b: exclusive scan of the 196 block sums (single block)
// ---------------------------------------------------------------------------
__global__ __launch_bounds__(256) void scan_offsets_kernel(int* __restrict__ bsum)
{
    __shared__ int s[256];
    const int t = threadIdx.x;
    const int x = (t < NB_SCAN) ? bsum[t] : 0;
    s[t] = x;
    __syncthreads();
    for (int off = 1; off < 256; off <<= 1) {
        const int v = (t >= off) ? s[t - off] : 0;
        __syncthreads();
        s[t] += v;
        __syncthreads();
    }
    if (t < NB_SCAN) bsum[t] = s[t] - x;   // exclusive
}

// ---------------------------------------------------------------------------
// Kernel 3c: final scan — node_start[i] and cursor[i] = global exclusive sum
// ---------------------------------------------------------------------------
__global__ __launch_bounds__(256) void scan_final_kernel(
    const int* __restrict__ bsum, int* __restrict__ cursor,
    int* __restrict__ node_start, int E)
{
    __shared__ int s[256];
    const int t = threadIdx.x;
    const int i = blockIdx.x * 256 + t;
    const int x = (i < N_NODES) ? cursor[i] : 0;
    s[t] = x;
    __syncthreads();
    for (int off = 1; off < 256; off <<= 1) {
        const int v = (t >= off) ? s[t - off] : 0;
        __syncthreads();
        s[t] += v;
        __syncthreads();
    }
    const int start = bsum[blockIdx.x] + (s[t] - x);
    if (i < N_NODES) {
        node_start[i] = start;
        cursor[i]     = start;
    }
    if (i == 0) node_start[N_NODES] = E;
}

// ---------------------------------------------------------------------------
// Kernel 4: scatter packed edge records to dst-sorted order
// ---------------------------------------------------------------------------
__global__ __launch_bounds__(256) void scatter_kernel(
    const int* __restrict__ src, const int* __restrict__ dst,
    const float* __restrict__ w0, const float* __restrict__ w1,
    int* __restrict__ cursor, int4* __restrict__ edges, int E)
{
    const int e = blockIdx.x * 256 + threadIdx.x;
    if (e >= E) return;
    const int d   = dst[e];
    const int pos = atomicAdd(&cursor[d], 1);
    edges[pos] = make_int4(src[e], __float_as_int(w0[e]), __float_as_int(w1[e]), 0);
}

// ---------------------------------------------------------------------------
// Kernel 5: gather aggregation — one 64-lane wave per dst node. Per edge,
// ONE dwordx2 gather per lane from the interleaved mv buffer; edge loop
// unrolled 4x for memory-level parallelism. Zero atomics.
// ---------------------------------------------------------------------------
__global__ __launch_bounds__(256) void agg_kernel(
    const ushort_t* __restrict__ mv,
    const int4* __restrict__ edges, const int* __restrict__ node_start,
    float* __restrict__ out_m, float* __restrict__ out_v)
{
    const int node = blockIdx.x * 4 + (threadIdx.x >> 6);
    const int lane = threadIdx.x & 63;
    if (node >= N_NODES) return;

    const int j0 = node_start[node];
    const int j1 = node_start[node + 1];

    float m0 = 0.f, m1 = 0.f, v0 = 0.f, v1 = 0.f;

    int j = j0;
    for (; j + 4 <= j1; j += 4) {
        const int4 r0 = edges[j + 0];
        const int4 r1 = edges[j + 1];
        const int4 r2 = edges[j + 2];
        const int4 r3 = edges[j + 3];
        const uint2 g0 = ((const uint2*)(mv + (size_t)r0.x * 256))[lane];
        const uint2 g1 = ((const uint2*)(mv + (size_t)r1.x * 256))[lane];
        const uint2 g2 = ((const uint2*)(mv + (size_t)r2.x * 256))[lane];
        const uint2 g3 = ((const uint2*)(mv + (size_t)r3.x * 256))[lane];

        float a0, a1;
        a0 = __int_as_float(r0.y); a1 = __int_as_float(r0.z);
        m0 = fmaf(a0, __uint_as_float(g0.x << 16),         m0);
        m1 = fmaf(a0, __uint_as_float(g0.x & 0xffff0000u), m1);
        v0 = fmaf(a1, __uint_as_float(g0.y << 16),         v0);
        v1 = fmaf(a1, __uint_as_float(g0.y & 0xffff0000u), v1);
        a0 = __int_as_float(r1.y); a1 = __int_as_float(r1.z);
        m0 = fmaf(a0, __uint_as_float(g1.x << 16),         m0);
        m1 = fmaf(a0, __uint_as_float(g1.x & 0xffff0000u), m1);
        v0 = fmaf(a1, __uint_as_float(g1.y << 16),         v0);
        v1 = fmaf(a1, __uint_as_float(g1.y & 0xffff0000u), v1);
        a0 = __int_as_float(r2.y); a1 = __int_as_float(r2.z);
        m0 = fmaf(a0, __uint_as_float(g2.x << 16),         m0);
        m1 = fmaf(a0, __uint_as_float(g2.x & 0xffff0000u), m1);
        v0 = fmaf(a1, __uint_as_float(g2.y << 16),         v0);
        v1 = fmaf(a1, __uint_as_float(g2.y & 0xffff0000u), v1);
        a0 = __int_as_float(r3.y); a1 = __int_as_float(r3.z);
        m0 = fmaf(a0, __uint_as_float(g3.x << 16),         m0);
        m1 = fmaf(a0, __uint_as_float(g3.x & 0xffff0000u), m1);
        v0 = fmaf(a1, __uint_as_float(g3.y << 16),         v0);
        v1 = fmaf(a1, __uint_as_float(g3.y & 0xffff0000u), v1);
    }
    for (; j < j1; ++j) {
        const int4 r = edges[j];
        const uint2 g = ((const uint2*)(mv + (size_t)r.x * 256))[lane];
        const float a0 = __int_as_float(r.y);
        const float a1 = __int_as_float(r.z);
        m0 = fmaf(a0, __uint_as_float(g.x << 16),         m0);
        m1 = fmaf(a0, __uint_as_float(g.x & 0xffff0000u), m1);
        v0 = fmaf(a1, __uint_as_float(g.y << 16),         v0);
        v1 = fmaf(a1, __uint_as_float(g.y & 0xffff0000u), v1);
    }

    *(float2*)(out_m + (size_t)node * DOUT + lane * 2) = make_float2(m0, m1);
    *(float2*)(out_v + (size_t)node * DOUT + lane * 2) = make_float2(v0, v1);
}

// ---------------------------------------------------------------------------
extern "C" void kernel_launch(void* const* d_in, const int* in_sizes, int n_in,
                              void* d_out, int out_size, void* d_ws, size_t ws_size,
                              hipStream_t stream) {
    const float* mean = (const float*)d_in[0];
    const float* var  = (const float*)d_in[1];
    const float* Wm   = (const float*)d_in[2];
    const float* bm   = (const float*)d_in[3];
    const float* Wv   = (const float*)d_in[4];
    const float* bv   = (const float*)d_in[5];
    const float* a0   = (const float*)d_in[6];
    const float* a1   = (const float*)d_in[7];
    const int*   es   = (const int*)d_in[8];
    const int*   ed   = (const int*)d_in[9];
    const int    E    = in_sizes[6];

    // Workspace layout:
    //   mv combined [N][256] bf16  25.6 MB
    //   edges [E] int4             12.8 MB
    //   node_start [N+1] / cursor [N] / bsum / W-fragments
    char* ws = (char*)d_ws;
    ushort_t* mv        = (ushort_t*)ws;
    int4*  edges        = (int4*)(ws + 25600000);
    int*   node_start   = (int*) (ws + 38400000);
    int*   cursor       = (int*) (ws + 38400000 + 200016);
    int*   bsum         = (int*) (ws + 38400000 + 200016 + 200000);
    ushort_t* wfm       = (ushort_t*)(ws + 38400000 + 200016 + 200000 + 1024);
    ushort_t* wfv       = wfm + 16384;

    float* out_m = (float*)d_out;
    float* out_v = out_m + (size_t)N_NODES * DOUT;

    // counts must start at zero (ws is poisoned 0xAA each call)
    hipMemsetAsync(cursor, 0, (size_t)N_NODES * sizeof(int), stream);

    prep_w_kernel<<<64, 256, 0, stream>>>(Wm, Wv, wfm, wfv);

    proj_mfma_kernel<<<(N_WAVES + 3) / 4, 256, 0, stream>>>(
        mean, var, bm, bv, wfm, wfv, mv);

    const int eb = (E + 255) / 256;
    count_kernel       <<<eb,      256, 0, stream>>>(ed, cursor, E);
    scan_bsum_kernel   <<<NB_SCAN, 256, 0, stream>>>(cursor, bsum);
    scan_offsets_kernel<<<1,       256, 0, stream>>>(bsum);
    scan_final_kernel  <<<NB_SCAN, 256, 0, stream>>>(bsum, cursor, node_start, E);
    scatter_kernel     <<<eb,      256, 0, stream>>>(es, ed, a0, a1, cursor, edges, E);

    agg_kernel<<<(N_NODES + 3) / 4, 256, 0, stream>>>(
        mv, edges, node_start, out_m, out_v);
}

// Round 5
// 241.796 us; speedup vs baseline: 12.4109x; 1.2533x over previous
//
#include <hip/hip_runtime.h>
#include <hip/hip_bf16.h>
#include <math.h>

#define N_NODES 50000
#define DIN     128
#define DOUT    128
#define EPS_    1e-6f
#define N_WAVES 3125         // N_NODES / 16 rows per wave (exact)
#define NBKT    196          // coarse buckets: dst>>8 (256 nodes each)
#define EPB     4096         // edges per phase-A block
#define SLOT_CAP 5120        // records per bucket slot (avg 4082, +16 sigma)

typedef __attribute__((ext_vector_type(8))) short  bf16x8;
typedef __attribute__((ext_vector_type(4))) float  f32x4;
typedef unsigned short ushort_t;

// round-to-nearest-even fp32 -> bf16 (finite inputs)
__device__ __forceinline__ ushort_t f2bf(float f) {
    unsigned u = __float_as_uint(f);
    return (ushort_t)((u + 0x7fffu + ((u >> 16) & 1u)) >> 16);
}

// ---------------------------------------------------------------------------
// Kernel 0: pre-pack Wm/Wv (fp32 row-major [k][n]) into bf16 B-fragment order
// for mfma_f32_16x16x32_bf16.
// ---------------------------------------------------------------------------
__global__ __launch_bounds__(256) void prep_w_kernel(
    const float* __restrict__ Wm, const float* __restrict__ Wv,
    ushort_t* __restrict__ fm, ushort_t* __restrict__ fv)
{
    const int gid = blockIdx.x * 256 + threadIdx.x;   // 16384 threads
    const int k = gid >> 7, n = gid & 127;
    const int ct = n >> 4, kk = k >> 5, quad = (k >> 3) & 3, j = k & 7;
    const int idx = ((ct * 4 + kk) * 64 + quad * 16 + (n & 15)) * 8 + j;
    fm[idx] = f2bf(Wm[gid]);
    fv[idx] = f2bf(Wv[gid]);
}

// ---------------------------------------------------------------------------
// Kernel 1: MFMA projection + ELU/ReLU + gate. Writes combined bf16 buffer
// mv[row][256]: pair p stores {m_2p, m_2p+1, v_2p, v_2p+1} so agg fetches
// both matrices with one dwordx2 per lane.
// ---------------------------------------------------------------------------
__global__ __launch_bounds__(256) void proj_mfma_kernel(
    const float* __restrict__ mean, const float* __restrict__ var,
    const float* __restrict__ bm,   const float* __restrict__ bv,
    const ushort_t* __restrict__ wfm, const ushort_t* __restrict__ wfv,
    ushort_t* __restrict__ mv)
{
    const int wave = blockIdx.x * 4 + (threadIdx.x >> 6);
    if (wave >= N_WAVES) return;
    const int lane = threadIdx.x & 63;
    const int row0 = wave * 16;
    const int kq   = lane >> 4;             // 0..3
    const int arow = row0 + (lane & 15);

    f32x4 accm[8], accv[8];
#pragma unroll
    for (int ct = 0; ct < 8; ++ct) {
        accm[ct] = (f32x4){0.f, 0.f, 0.f, 0.f};
        accv[ct] = (f32x4){0.f, 0.f, 0.f, 0.f};
    }

    const float* mrow = mean + (size_t)arow * DIN;
    const float* vrow = var  + (size_t)arow * DIN;

#pragma unroll
    for (int kk = 0; kk < 4; ++kk) {
        const int kb = kk * 32 + kq * 8;
        const float4 am0 = *(const float4*)(mrow + kb);
        const float4 am1 = *(const float4*)(mrow + kb + 4);
        const float4 av0 = *(const float4*)(vrow + kb);
        const float4 av1 = *(const float4*)(vrow + kb + 4);
        bf16x8 a_m, a_v;
        a_m[0]=f2bf(am0.x); a_m[1]=f2bf(am0.y); a_m[2]=f2bf(am0.z); a_m[3]=f2bf(am0.w);
        a_m[4]=f2bf(am1.x); a_m[5]=f2bf(am1.y); a_m[6]=f2bf(am1.z); a_m[7]=f2bf(am1.w);
        a_v[0]=f2bf(av0.x); a_v[1]=f2bf(av0.y); a_v[2]=f2bf(av0.z); a_v[3]=f2bf(av0.w);
        a_v[4]=f2bf(av1.x); a_v[5]=f2bf(av1.y); a_v[6]=f2bf(av1.z); a_v[7]=f2bf(av1.w);

#pragma unroll
        for (int ct = 0; ct < 8; ++ct) {
            const bf16x8 b_m = *(const bf16x8*)(wfm + ((size_t)(ct * 4 + kk) * 64 + lane) * 8);
            const bf16x8 b_v = *(const bf16x8*)(wfv + ((size_t)(ct * 4 + kk) * 64 + lane) * 8);
            accm[ct] = __builtin_amdgcn_mfma_f32_16x16x32_bf16(a_m, b_m, accm[ct], 0, 0, 0);
            accv[ct] = __builtin_amdgcn_mfma_f32_16x16x32_bf16(a_v, b_v, accv[ct], 0, 0, 0);
        }
    }

#pragma unroll
    for (int ct = 0; ct < 8; ++ct) {
        const int col = ct * 16 + (lane & 15);
        const float bmc = bm[col];
        const float bvc = bv[col];
        const int pbase = (col >> 1) * 4 + (col & 1);   // pair-interleave offset
#pragma unroll
        for (int r = 0; r < 4; ++r) {
            const int row = row0 + kq * 4 + r;
            float m = accm[ct][r] + bmc;
            m = (m > 0.0f) ? m : (expf(m) - 1.0f);           // ELU
            float v = accv[ct][r] + bvc;
            v = ((v > 0.0f) ? v : 0.0f) + EPS_;              // ReLU + eps
            const float att = expf(-v);
            ushort_t* rowp = mv + (size_t)row * 256;
            rowp[pbase]     = f2bf(m * att);
            rowp[pbase + 2] = f2bf(v * att * att);
        }
    }
}

// ---------------------------------------------------------------------------
// Kernel 2 (phase A): coarse bucket sort. Each block takes EPB edges, bins
// them by dst>>8 in LDS, reserves global run space with ONE atomic per
// (block,bucket), and streams records out bin-major (coalesced runs).
// Record = uint2{ src | (dst&255)<<16 , w0_bf16 | w1_bf16<<16 }  (8 B).
// ---------------------------------------------------------------------------
__global__ __launch_bounds__(256) void bucketA_kernel(
    const int* __restrict__ src, const int* __restrict__ dst,
    const float* __restrict__ w0, const float* __restrict__ w1,
    int* __restrict__ gcur, uint2* __restrict__ slots, int E)
{
    __shared__ uint2 s_rec[EPB];
    __shared__ int   s_gpos[EPB];
    __shared__ int   s_hist[256];
    __shared__ int   s_scn[256];
    __shared__ int   s_cur[256];
    __shared__ int   s_base[256];

    const int t  = threadIdx.x;
    const int e0 = blockIdx.x * EPB;
    const int n  = min(EPB, E - e0);

    s_hist[t] = 0;
    __syncthreads();

    int   myb[16];
    uint2 myr[16];
#pragma unroll
    for (int j = 0; j < 16; ++j) {
        const int e = e0 + t + j * 256;
        if (e < E) {
            const int d = dst[e];
            const int b = d >> 8;
            myb[j] = b;
            myr[j].x = (unsigned)src[e] | ((unsigned)(d & 255) << 16);
            myr[j].y = (unsigned)f2bf(w0[e]) | ((unsigned)f2bf(w1[e]) << 16);
            atomicAdd(&s_hist[b], 1);
        } else myb[j] = -1;
    }
    __syncthreads();

    // reserve global run space (one global atomic per bucket per block)
    if (t < NBKT) {
        const int c = s_hist[t];
        s_base[t] = t * SLOT_CAP + (c ? atomicAdd(&gcur[t], c) : 0);
    }
    // exclusive scan of hist -> s_scn
    const int x = s_hist[t];
    s_scn[t] = x;
    __syncthreads();
    for (int off = 1; off < 256; off <<= 1) {
        const int v = (t >= off) ? s_scn[t - off] : 0;
        __syncthreads();
        s_scn[t] += v;
        __syncthreads();
    }
    const int excl = s_scn[t] - x;
    __syncthreads();
    s_scn[t] = excl;
    s_cur[t] = 0;
    __syncthreads();

    // re-bin into LDS (bin-major) and precompute global positions
#pragma unroll
    for (int j = 0; j < 16; ++j) {
        if (myb[j] >= 0) {
            const int r = atomicAdd(&s_cur[myb[j]], 1);
            const int p = s_scn[myb[j]] + r;
            s_rec[p]  = myr[j];
            s_gpos[p] = s_base[myb[j]] + r;
        }
    }
    __syncthreads();

    // stream out: consecutive i within a run -> consecutive global positions
    for (int i = t; i < n; i += 256)
        slots[s_gpos[i]] = s_rec[i];
}

// ---------------------------------------------------------------------------
// Kernel 3: exclusive scan of 196 bucket counts -> bucket_base (single block)
// ---------------------------------------------------------------------------
__global__ __launch_bounds__(256) void bucket_scan_kernel(
    const int* __restrict__ gcur, int* __restrict__ bbase)
{
    __shared__ int s[256];
    const int t = threadIdx.x;
    const int x = (t < NBKT) ? gcur[t] : 0;
    s[t] = x;
    __syncthreads();
    for (int off = 1; off < 256; off <<= 1) {
        const int v = (t >= off) ? s[t - off] : 0;
        __syncthreads();
        s[t] += v;
        __syncthreads();
    }
    if (t < NBKT) bbase[t] = s[t] - x;   // exclusive
}

// ---------------------------------------------------------------------------
// Kernel 4 (phase B): fine counting sort within each bucket (one block per
// bucket). Records held in registers; fine 256-bin LDS histogram + scan
// produces node_start directly; records written to final dst-sorted array.
// ---------------------------------------------------------------------------
__global__ __launch_bounds__(256) void bucketB_kernel(
    const int* __restrict__ gcur, const int* __restrict__ bbase,
    const uint2* __restrict__ slots, uint2* __restrict__ final_e,
    int* __restrict__ node_start)
{
    __shared__ int s_hist[256];
    __shared__ int s_scn[256];
    __shared__ int s_cur[256];

    const int b    = blockIdx.x;
    const int t    = threadIdx.x;
    const int cnt  = gcur[b];
    const int base = bbase[b];
    const uint2* slot = slots + (size_t)b * SLOT_CAP;

    s_hist[t] = 0;
    __syncthreads();

    uint2 myr[20];
    int   myf[20];
    int   k = 0;
    for (int i = t; i < cnt; i += 256) {
        const uint2 r = slot[i];
        const int f = (r.x >> 16) & 255;
        myr[k] = r; myf[k] = f; ++k;
        atomicAdd(&s_hist[f], 1);
    }
    __syncthreads();

    // exclusive scan -> s_scn
    const int x = s_hist[t];
    s_scn[t] = x;
    __syncthreads();
    for (int off = 1; off < 256; off <<= 1) {
        const int v = (t >= off) ? s_scn[t - off] : 0;
        __syncthreads();
        s_scn[t] += v;
        __syncthreads();
    }
    const int excl = s_scn[t] - x;
    __syncthreads();
    s_scn[t] = excl;
    __syncthreads();

    // node_start for this bucket's 256 nodes (+ sentinel at N_NODES)
    const int gidx = b * 256 + t;
    if (gidx <= N_NODES) node_start[gidx] = base + excl;

    s_cur[t] = excl;
    __syncthreads();

#pragma unroll
    for (int j = 0; j < 20; ++j) {
        if (j < k) {
            const int p = atomicAdd(&s_cur[myf[j]], 1);
            final_e[base + p] = myr[j];
        }
    }
}

// ---------------------------------------------------------------------------
// Kernel 5: gather aggregation — one 64-lane wave per dst node. Per edge,
// one 8 B record read + one 8 B dwordx2 gather per lane; unrolled 4x.
// ---------------------------------------------------------------------------
__global__ __launch_bounds__(256) void agg_kernel(
    const ushort_t* __restrict__ mv,
    const uint2* __restrict__ edges, const int* __restrict__ node_start,
    float* __restrict__ out_m, float* __restrict__ out_v)
{
    const int node = blockIdx.x * 4 + (threadIdx.x >> 6);
    const int lane = threadIdx.x & 63;
    if (node >= N_NODES) return;

    const int j0 = node_start[node];
    const int j1 = node_start[node + 1];

    float m0 = 0.f, m1 = 0.f, v0 = 0.f, v1 = 0.f;

    int j = j0;
    for (; j + 4 <= j1; j += 4) {
        const uint2 r0 = edges[j + 0];
        const uint2 r1 = edges[j + 1];
        const uint2 r2 = edges[j + 2];
        const uint2 r3 = edges[j + 3];
        const uint2 g0 = ((const uint2*)(mv + (size_t)(r0.x & 0xffffu) * 256))[lane];
        const uint2 g1 = ((const uint2*)(mv + (size_t)(r1.x & 0xffffu) * 256))[lane];
        const uint2 g2 = ((const uint2*)(mv + (size_t)(r2.x & 0xffffu) * 256))[lane];
        const uint2 g3 = ((const uint2*)(mv + (size_t)(r3.x & 0xffffu) * 256))[lane];

        float a0, a1;
        a0 = __uint_as_float(r0.y << 16); a1 = __uint_as_float(r0.y & 0xffff0000u);
        m0 = fmaf(a0, __uint_as_float(g0.x << 16),         m0);
        m1 = fmaf(a0, __uint_as_float(g0.x & 0xffff0000u), m1);
        v0 = fmaf(a1, __uint_as_float(g0.y << 16),         v0);
        v1 = fmaf(a1, __uint_as_float(g0.y & 0xffff0000u), v1);
        a0 = __uint_as_float(r1.y << 16); a1 = __uint_as_float(r1.y & 0xffff0000u);
        m0 = fmaf(a0, __uint_as_float(g1.x << 16),         m0);
        m1 = fmaf(a0, __uint_as_float(g1.x & 0xffff0000u), m1);
        v0 = fmaf(a1, __uint_as_float(g1.y << 16),         v0);
        v1 = fmaf(a1, __uint_as_float(g1.y & 0xffff0000u), v1);
        a0 = __uint_as_float(r2.y << 16); a1 = __uint_as_float(r2.y & 0xffff0000u);
        m0 = fmaf(a0, __uint_as_float(g2.x << 16),         m0);
        m1 = fmaf(a0, __uint_as_float(g2.x & 0xffff0000u), m1);
        v0 = fmaf(a1, __uint_as_float(g2.y << 16),         v0);
        v1 = fmaf(a1, __uint_as_float(g2.y & 0xffff0000u), v1);
        a0 = __uint_as_float(r3.y << 16); a1 = __uint_as_float(r3.y & 0xffff0000u);
        m0 = fmaf(a0, __uint_as_float(g3.x << 16),         m0);
        m1 = fmaf(a0, __uint_as_float(g3.x & 0xffff0000u), m1);
        v0 = fmaf(a1, __uint_as_float(g3.y << 16),         v0);
        v1 = fmaf(a1, __uint_as_float(g3.y & 0xffff0000u), v1);
    }
    for (; j < j1; ++j) {
        const uint2 r = edges[j];
        const uint2 g = ((const uint2*)(mv + (size_t)(r.x & 0xffffu) * 256))[lane];
        const float a0 = __uint_as_float(r.y << 16);
        const float a1 = __uint_as_float(r.y & 0xffff0000u);
        m0 = fmaf(a0, __uint_as_float(g.x << 16),         m0);
        m1 = fmaf(a0, __uint_as_float(g.x & 0xffff0000u), m1);
        v0 = fmaf(a1, __uint_as_float(g.y << 16),         v0);
        v1 = fmaf(a1, __uint_as_float(g.y & 0xffff0000u), v1);
    }

    *(float2*)(out_m + (size_t)node * DOUT + lane * 2) = make_float2(m0, m1);
    *(float2*)(out_v + (size_t)node * DOUT + lane * 2) = make_float2(v0, v1);
}

// ---------------------------------------------------------------------------
extern "C" void kernel_launch(void* const* d_in, const int* in_sizes, int n_in,
                              void* d_out, int out_size, void* d_ws, size_t ws_size,
                              hipStream_t stream) {
    const float* mean = (const float*)d_in[0];
    const float* var  = (const float*)d_in[1];
    const float* Wm   = (const float*)d_in[2];
    const float* bm   = (const float*)d_in[3];
    const float* Wv   = (const float*)d_in[4];
    const float* bv   = (const float*)d_in[5];
    const float* a0   = (const float*)d_in[6];
    const float* a1   = (const float*)d_in[7];
    const int*   es   = (const int*)d_in[8];
    const int*   ed   = (const int*)d_in[9];
    const int    E    = in_sizes[6];

    // Workspace layout (byte offsets):
    //   mv [N][256] bf16           0          .. 25,600,000
    //   slots uint2[196*5120]      25,600,000 .. 33,628,160
    //   final_e uint2[E]           33,628,160 .. 40,028,160
    //   node_start int[N+1]        40,028,160 .. 40,228,164
    //   gcur int[196]              40,228,164 .. 40,228,948
    //   bbase int[196]             40,228,948 .. 40,229,732
    //   wfm/wfv bf16 frags         40,229,744 .. 40,295,280   (~40.3 MB)
    char* ws = (char*)d_ws;
    ushort_t* mv        = (ushort_t*)ws;
    uint2* slots        = (uint2*)(ws + 25600000);
    uint2* final_e      = (uint2*)(ws + 33628160);
    int*   node_start   = (int*)  (ws + 40028160);
    int*   gcur         = (int*)  (ws + 40228164);
    int*   bbase        = (int*)  (ws + 40228948);
    ushort_t* wfm       = (ushort_t*)(ws + 40229744);
    ushort_t* wfv       = wfm + 16384;

    float* out_m = (float*)d_out;
    float* out_v = out_m + (size_t)N_NODES * DOUT;

    // bucket cursors must start at zero (ws is poisoned 0xAA each call)
    hipMemsetAsync(gcur, 0, NBKT * sizeof(int), stream);

    prep_w_kernel<<<64, 256, 0, stream>>>(Wm, Wv, wfm, wfv);

    proj_mfma_kernel<<<(N_WAVES + 3) / 4, 256, 0, stream>>>(
        mean, var, bm, bv, wfm, wfv, mv);

    bucketA_kernel<<<(E + EPB - 1) / EPB, 256, 0, stream>>>(
        es, ed, a0, a1, gcur, slots, E);
    bucket_scan_kernel<<<1, 256, 0, stream>>>(gcur, bbase);
    bucketB_kernel<<<NBKT, 256, 0, stream>>>(
        gcur, bbase, slots, final_e, node_start);

    agg_kernel<<<(N_NODES + 3) / 4, 256, 0, stream>>>(
        mv, final_e, node_start, out_m, out_v);
}

// Round 6
// 232.662 us; speedup vs baseline: 12.8981x; 1.0393x over previous
//
#include <hip/hip_runtime.h>
#include <hip/hip_bf16.h>
#include <math.h>

#define N_NODES 50000
#define DIN     128
#define DOUT    128
#define EPS_    1e-6f
#define N_WAVES 3125         // N_NODES / 16 rows per wave (exact)
#define NBKT    196          // coarse buckets: dst>>8 (256 nodes each)
#define EPB     4096         // edges per phase-A block
#define SLOT_CAP 5120        // records per bucket slot (avg 4082, +16 sigma)

typedef __attribute__((ext_vector_type(8))) short  bf16x8;
typedef __attribute__((ext_vector_type(4))) float  f32x4;
typedef unsigned short ushort_t;

// round-to-nearest-even fp32 -> bf16 (finite inputs)
__device__ __forceinline__ ushort_t f2bf(float f) {
    unsigned u = __float_as_uint(f);
    return (ushort_t)((u + 0x7fffu + ((u >> 16) & 1u)) >> 16);
}
__device__ __forceinline__ float bflo(unsigned u) { return __uint_as_float(u << 16); }
__device__ __forceinline__ float bfhi(unsigned u) { return __uint_as_float(u & 0xffff0000u); }

// ---------------------------------------------------------------------------
// Kernel 0: pre-pack Wm/Wv into bf16 B-fragment order for
// mfma_f32_16x16x32_bf16; also zeroes the bucket cursors (gcur).
// ---------------------------------------------------------------------------
__global__ __launch_bounds__(256) void prep_w_kernel(
    const float* __restrict__ Wm, const float* __restrict__ Wv,
    ushort_t* __restrict__ fm, ushort_t* __restrict__ fv,
    int* __restrict__ gcur)
{
    const int gid = blockIdx.x * 256 + threadIdx.x;   // 16384 threads
    if (gid < NBKT) gcur[gid] = 0;
    const int k = gid >> 7, n = gid & 127;
    const int ct = n >> 4, kk = k >> 5, quad = (k >> 3) & 3, j = k & 7;
    const int idx = ((ct * 4 + kk) * 64 + quad * 16 + (n & 15)) * 8 + j;
    fm[idx] = f2bf(Wm[gid]);
    fv[idx] = f2bf(Wv[gid]);
}

// ---------------------------------------------------------------------------
// Kernel 1: MFMA projection + ELU/ReLU + gate. Writes combined bf16 buffer
// mv[row][256]: pair p stores {m_2p, m_2p+1, v_2p, v_2p+1}.
// ---------------------------------------------------------------------------
__global__ __launch_bounds__(256) void proj_mfma_kernel(
    const float* __restrict__ mean, const float* __restrict__ var,
    const float* __restrict__ bm,   const float* __restrict__ bv,
    const ushort_t* __restrict__ wfm, const ushort_t* __restrict__ wfv,
    ushort_t* __restrict__ mv)
{
    const int wave = blockIdx.x * 4 + (threadIdx.x >> 6);
    if (wave >= N_WAVES) return;
    const int lane = threadIdx.x & 63;
    const int row0 = wave * 16;
    const int kq   = lane >> 4;             // 0..3
    const int arow = row0 + (lane & 15);

    f32x4 accm[8], accv[8];
#pragma unroll
    for (int ct = 0; ct < 8; ++ct) {
        accm[ct] = (f32x4){0.f, 0.f, 0.f, 0.f};
        accv[ct] = (f32x4){0.f, 0.f, 0.f, 0.f};
    }

    const float* mrow = mean + (size_t)arow * DIN;
    const float* vrow = var  + (size_t)arow * DIN;

#pragma unroll
    for (int kk = 0; kk < 4; ++kk) {
        const int kb = kk * 32 + kq * 8;
        const float4 am0 = *(const float4*)(mrow + kb);
        const float4 am1 = *(const float4*)(mrow + kb + 4);
        const float4 av0 = *(const float4*)(vrow + kb);
        const float4 av1 = *(const float4*)(vrow + kb + 4);
        bf16x8 a_m, a_v;
        a_m[0]=f2bf(am0.x); a_m[1]=f2bf(am0.y); a_m[2]=f2bf(am0.z); a_m[3]=f2bf(am0.w);
        a_m[4]=f2bf(am1.x); a_m[5]=f2bf(am1.y); a_m[6]=f2bf(am1.z); a_m[7]=f2bf(am1.w);
        a_v[0]=f2bf(av0.x); a_v[1]=f2bf(av0.y); a_v[2]=f2bf(av0.z); a_v[3]=f2bf(av0.w);
        a_v[4]=f2bf(av1.x); a_v[5]=f2bf(av1.y); a_v[6]=f2bf(av1.z); a_v[7]=f2bf(av1.w);

#pragma unroll
        for (int ct = 0; ct < 8; ++ct) {
            const bf16x8 b_m = *(const bf16x8*)(wfm + ((size_t)(ct * 4 + kk) * 64 + lane) * 8);
            const bf16x8 b_v = *(const bf16x8*)(wfv + ((size_t)(ct * 4 + kk) * 64 + lane) * 8);
            accm[ct] = __builtin_amdgcn_mfma_f32_16x16x32_bf16(a_m, b_m, accm[ct], 0, 0, 0);
            accv[ct] = __builtin_amdgcn_mfma_f32_16x16x32_bf16(a_v, b_v, accv[ct], 0, 0, 0);
        }
    }

#pragma unroll
    for (int ct = 0; ct < 8; ++ct) {
        const int col = ct * 16 + (lane & 15);
        const float bmc = bm[col];
        const float bvc = bv[col];
        const int pbase = (col >> 1) * 4 + (col & 1);   // pair-interleave offset
#pragma unroll
        for (int r = 0; r < 4; ++r) {
            const int row = row0 + kq * 4 + r;
            float m = accm[ct][r] + bmc;
            m = (m > 0.0f) ? m : (expf(m) - 1.0f);           // ELU
            float v = accv[ct][r] + bvc;
            v = ((v > 0.0f) ? v : 0.0f) + EPS_;              // ReLU + eps
            const float att = expf(-v);
            ushort_t* rowp = mv + (size_t)row * 256;
            rowp[pbase]     = f2bf(m * att);
            rowp[pbase + 2] = f2bf(v * att * att);
        }
    }
}

// ---------------------------------------------------------------------------
// Kernel 2 (phase A): coarse bucket sort by dst>>8.
// Record = uint2{ src | (dst&255)<<16 , w0_bf16 | w1_bf16<<16 }  (8 B).
// ---------------------------------------------------------------------------
__global__ __launch_bounds__(256) void bucketA_kernel(
    const int* __restrict__ src, const int* __restrict__ dst,
    const float* __restrict__ w0, const float* __restrict__ w1,
    int* __restrict__ gcur, uint2* __restrict__ slots, int E)
{
    __shared__ uint2 s_rec[EPB];
    __shared__ int   s_gpos[EPB];
    __shared__ int   s_hist[256];
    __shared__ int   s_scn[256];
    __shared__ int   s_cur[256];
    __shared__ int   s_base[256];

    const int t  = threadIdx.x;
    const int e0 = blockIdx.x * EPB;
    const int n  = min(EPB, E - e0);

    s_hist[t] = 0;
    __syncthreads();

    int   myb[16];
    uint2 myr[16];
#pragma unroll
    for (int j = 0; j < 16; ++j) {
        const int e = e0 + t + j * 256;
        if (e < E) {
            const int d = dst[e];
            const int b = d >> 8;
            myb[j] = b;
            myr[j].x = (unsigned)src[e] | ((unsigned)(d & 255) << 16);
            myr[j].y = (unsigned)f2bf(w0[e]) | ((unsigned)f2bf(w1[e]) << 16);
            atomicAdd(&s_hist[b], 1);
        } else myb[j] = -1;
    }
    __syncthreads();

    if (t < NBKT) {
        const int c = s_hist[t];
        s_base[t] = t * SLOT_CAP + (c ? atomicAdd(&gcur[t], c) : 0);
    }
    const int x = s_hist[t];
    s_scn[t] = x;
    __syncthreads();
    for (int off = 1; off < 256; off <<= 1) {
        const int v = (t >= off) ? s_scn[t - off] : 0;
        __syncthreads();
        s_scn[t] += v;
        __syncthreads();
    }
    const int excl = s_scn[t] - x;
    __syncthreads();
    s_scn[t] = excl;
    s_cur[t] = 0;
    __syncthreads();

#pragma unroll
    for (int j = 0; j < 16; ++j) {
        if (myb[j] >= 0) {
            const int r = atomicAdd(&s_cur[myb[j]], 1);
            const int p = s_scn[myb[j]] + r;
            s_rec[p]  = myr[j];
            s_gpos[p] = s_base[myb[j]] + r;
        }
    }
    __syncthreads();

    for (int i = t; i < n; i += 256)
        slots[s_gpos[i]] = s_rec[i];
}

// ---------------------------------------------------------------------------
// Kernel 3 (phase B): fine counting sort within each bucket. Computes its own
// global base by reducing gcur[0..b) (fused former scan kernel); writes
// node_start directly and final records dst-sorted.
// ---------------------------------------------------------------------------
__global__ __launch_bounds__(256) void bucketB_kernel(
    const int* __restrict__ gcur,
    const uint2* __restrict__ slots, uint2* __restrict__ final_e,
    int* __restrict__ node_start)
{
    __shared__ int s_hist[256];
    __shared__ int s_scn[256];
    __shared__ int s_cur[256];
    __shared__ int s_red[256];

    const int b = blockIdx.x;
    const int t = threadIdx.x;

    // base = sum gcur[0..b)   (b < 256, one element per thread)
    s_red[t] = (t < b) ? gcur[t] : 0;
    s_hist[t] = 0;
    __syncthreads();
    for (int off = 128; off > 0; off >>= 1) {
        if (t < off) s_red[t] += s_red[t + off];
        __syncthreads();
    }
    const int base = s_red[0];
    const int cnt  = gcur[b];
    const uint2* slot = slots + (size_t)b * SLOT_CAP;

    uint2 myr[20];
    int   myf[20];
    int   k = 0;
    for (int i = t; i < cnt; i += 256) {
        const uint2 r = slot[i];
        const int f = (r.x >> 16) & 255;
        myr[k] = r; myf[k] = f; ++k;
        atomicAdd(&s_hist[f], 1);
    }
    __syncthreads();

    const int x = s_hist[t];
    s_scn[t] = x;
    __syncthreads();
    for (int off = 1; off < 256; off <<= 1) {
        const int v = (t >= off) ? s_scn[t - off] : 0;
        __syncthreads();
        s_scn[t] += v;
        __syncthreads();
    }
    const int excl = s_scn[t] - x;
    __syncthreads();

    const int gidx = b * 256 + t;
    if (gidx <= N_NODES) node_start[gidx] = base + excl;

    s_cur[t] = excl;
    __syncthreads();

#pragma unroll
    for (int j = 0; j < 20; ++j) {
        if (j < k) {
            const int p = atomicAdd(&s_cur[myf[j]], 1);
            final_e[base + p] = myr[j];
        }
    }
}

// ---------------------------------------------------------------------------
// Kernel 4: gather aggregation — one 64-lane wave per dst node, TWO edges per
// gather instruction: lanes 0-31 handle edge j, lanes 32-63 edge j+1; each
// lane reads 16 B (dwordx4) of the interleaved mv row. Cross-half combine via
// __shfl_xor(32); lanes 0-31 store float4. Zero atomics.
// ---------------------------------------------------------------------------
#define PAIR_FMA(RW, G) do {                                                 \
    const float a0 = bflo(RW), a1 = bfhi(RW);                                \
    am0 = fmaf(a0, bflo((G).x), am0); am1 = fmaf(a0, bfhi((G).x), am1);      \
    av0 = fmaf(a1, bflo((G).y), av0); av1 = fmaf(a1, bfhi((G).y), av1);      \
    am2 = fmaf(a0, bflo((G).z), am2); am3 = fmaf(a0, bfhi((G).z), am3);      \
    av2 = fmaf(a1, bflo((G).w), av2); av3 = fmaf(a1, bfhi((G).w), av3);      \
} while (0)

__global__ __launch_bounds__(256) void agg_kernel(
    const ushort_t* __restrict__ mv,
    const uint2* __restrict__ edges, const int* __restrict__ node_start,
    float* __restrict__ out_m, float* __restrict__ out_v)
{
    const int node = blockIdx.x * 4 + (threadIdx.x >> 6);
    const int lane = threadIdx.x & 63;
    const int half = lane >> 5;
    const int l    = lane & 31;
    if (node >= N_NODES) return;

    const int j0 = node_start[node];
    const int j1 = node_start[node + 1];

    float am0=0.f, am1=0.f, am2=0.f, am3=0.f;
    float av0=0.f, av1=0.f, av2=0.f, av3=0.f;

    int j = j0;

    // align j to even for uint4 record loads
    if ((j & 1) && j < j1) {
        const uint2 r = edges[j];
        const unsigned rw = half ? 0u : r.y;     // upper half contributes zero
        const uint4 g = *(const uint4*)(mv + (size_t)(r.x & 0xffffu) * 256 + l * 8);
        PAIR_FMA(rw, g);
        ++j;
    }

    // 4 pairs (8 edges) per iteration
    for (; j + 8 <= j1; j += 8) {
        const uint4 e0 = *(const uint4*)(edges + j + 0);
        const uint4 e1 = *(const uint4*)(edges + j + 2);
        const uint4 e2 = *(const uint4*)(edges + j + 4);
        const uint4 e3 = *(const uint4*)(edges + j + 6);
        const unsigned s0 = half ? e0.z : e0.x, w0 = half ? e0.w : e0.y;
        const unsigned s1 = half ? e1.z : e1.x, w1 = half ? e1.w : e1.y;
        const unsigned s2 = half ? e2.z : e2.x, w2 = half ? e2.w : e2.y;
        const unsigned s3 = half ? e3.z : e3.x, w3 = half ? e3.w : e3.y;
        const uint4 g0 = *(const uint4*)(mv + (size_t)(s0 & 0xffffu) * 256 + l * 8);
        const uint4 g1 = *(const uint4*)(mv + (size_t)(s1 & 0xffffu) * 256 + l * 8);
        const uint4 g2 = *(const uint4*)(mv + (size_t)(s2 & 0xffffu) * 256 + l * 8);
        const uint4 g3 = *(const uint4*)(mv + (size_t)(s3 & 0xffffu) * 256 + l * 8);
        PAIR_FMA(w0, g0);
        PAIR_FMA(w1, g1);
        PAIR_FMA(w2, g2);
        PAIR_FMA(w3, g3);
    }

    // remaining full pairs
    for (; j + 2 <= j1; j += 2) {
        const uint4 e = *(const uint4*)(edges + j);
        const unsigned s = half ? e.z : e.x, w = half ? e.w : e.y;
        const uint4 g = *(const uint4*)(mv + (size_t)(s & 0xffffu) * 256 + l * 8);
        PAIR_FMA(w, g);
    }

    // odd tail edge
    if (j < j1) {
        const uint2 r = edges[j];
        const unsigned rw = half ? 0u : r.y;
        const uint4 g = *(const uint4*)(mv + (size_t)(r.x & 0xffffu) * 256 + l * 8);
        PAIR_FMA(rw, g);
    }

    // combine the two halves
    am0 += __shfl_xor(am0, 32); am1 += __shfl_xor(am1, 32);
    am2 += __shfl_xor(am2, 32); am3 += __shfl_xor(am3, 32);
    av0 += __shfl_xor(av0, 32); av1 += __shfl_xor(av1, 32);
    av2 += __shfl_xor(av2, 32); av3 += __shfl_xor(av3, 32);

    if (half == 0) {
        *(float4*)(out_m + (size_t)node * DOUT + l * 4) = make_float4(am0, am1, am2, am3);
        *(float4*)(out_v + (size_t)node * DOUT + l * 4) = make_float4(av0, av1, av2, av3);
    }
}

// ---------------------------------------------------------------------------
extern "C" void kernel_launch(void* const* d_in, const int* in_sizes, int n_in,
                              void* d_out, int out_size, void* d_ws, size_t ws_size,
                              hipStream_t stream) {
    const float* mean = (const float*)d_in[0];
    const float* var  = (const float*)d_in[1];
    const float* Wm   = (const float*)d_in[2];
    const float* bm   = (const float*)d_in[3];
    const float* Wv   = (const float*)d_in[4];
    const float* bv   = (const float*)d_in[5];
    const float* a0   = (const float*)d_in[6];
    const float* a1   = (const float*)d_in[7];
    const int*   es   = (const int*)d_in[8];
    const int*   ed   = (const int*)d_in[9];
    const int    E    = in_sizes[6];

    // Workspace layout (byte offsets, all 16B-aligned):
    //   mv [N][256] bf16           0          .. 25,600,000
    //   slots uint2[196*5120]      25,600,000 .. 33,628,160
    //   final_e uint2[E]           33,628,160 .. 40,028,160
    //   node_start int[N+1]        40,028,160 .. 40,228,164
    //   gcur int[196]              40,228,176 .. 40,228,960
    //   wfm/wfv bf16 frags         40,228,976 .. 40,294,512
    char* ws = (char*)d_ws;
    ushort_t* mv        = (ushort_t*)ws;
    uint2* slots        = (uint2*)(ws + 25600000);
    uint2* final_e      = (uint2*)(ws + 33628160);
    int*   node_start   = (int*)  (ws + 40028160);
    int*   gcur         = (int*)  (ws + 40228176);
    ushort_t* wfm       = (ushort_t*)(ws + 40228976);
    ushort_t* wfv       = wfm + 16384;

    float* out_m = (float*)d_out;
    float* out_v = out_m + (size_t)N_NODES * DOUT;

    prep_w_kernel<<<64, 256, 0, stream>>>(Wm, Wv, wfm, wfv, gcur);

    proj_mfma_kernel<<<(N_WAVES + 3) / 4, 256, 0, stream>>>(
        mean, var, bm, bv, wfm, wfv, mv);

    bucketA_kernel<<<(E + EPB - 1) / EPB, 256, 0, stream>>>(
        es, ed, a0, a1, gcur, slots, E);
    bucketB_kernel<<<NBKT, 256, 0, stream>>>(
        gcur, slots, final_e, node_start);

    agg_kernel<<<(N_NODES + 3) / 4, 256, 0, stream>>>(
        mv, final_e, node_start, out_m, out_v);
}

// Round 7
// 211.757 us; speedup vs baseline: 14.1714x; 1.0987x over previous
//
#include <hip/hip_runtime.h>
#include <hip/hip_bf16.h>
#include <math.h>

#define N_NODES 50000
#define DIN     128
#define DOUT    128
#define EPS_    1e-6f
#define N_WAVES 3125         // N_NODES / 16 rows per wave (exact)
#define NBKT    196          // coarse buckets: dst>>8 (256 nodes each)
#define EPB     4096         // edges per bucketA block
#define SLOT_CAP 5120        // records per bucket slot (avg 4082)
#define NB_PROJ 782          // ceil(3125/4) proj blocks

typedef __attribute__((ext_vector_type(8))) short  bf16x8;
typedef __attribute__((ext_vector_type(4))) float  f32x4;
typedef unsigned short ushort_t;

__device__ __forceinline__ ushort_t f2bf(float f) {
    unsigned u = __float_as_uint(f);
    return (ushort_t)((u + 0x7fffu + ((u >> 16) & 1u)) >> 16);
}
__device__ __forceinline__ float bflo(unsigned u) { return __uint_as_float(u << 16); }
__device__ __forceinline__ float bfhi(unsigned u) { return __uint_as_float(u & 0xffff0000u); }

// ---------------------------------------------------------------------------
// Kernel 0: pre-pack Wm/Wv into bf16 B-fragment order; zero bucket cursors.
// ---------------------------------------------------------------------------
__global__ __launch_bounds__(256) void prep_w_kernel(
    const float* __restrict__ Wm, const float* __restrict__ Wv,
    ushort_t* __restrict__ fm, ushort_t* __restrict__ fv,
    int* __restrict__ gcur)
{
    const int gid = blockIdx.x * 256 + threadIdx.x;   // 16384 threads
    if (gid < NBKT) gcur[gid] = 0;
    const int k = gid >> 7, n = gid & 127;
    const int ct = n >> 4, kk = k >> 5, quad = (k >> 3) & 3, j = k & 7;
    const int idx = ((ct * 4 + kk) * 64 + quad * 16 + (n & 15)) * 8 + j;
    fm[idx] = f2bf(Wm[gid]);
    fv[idx] = f2bf(Wv[gid]);
}

// ---------------------------------------------------------------------------
// Kernel 1 (FUSED): blocks [0,nA) run the coarse bucket sort (phase A);
// blocks [nA, nA+NB_PROJ) run the MFMA projection. The two are data-
// independent; fusing overlaps bucketA's LDS/atomic work with proj's
// memory-bound phase and saves a dispatch.
// ---------------------------------------------------------------------------
__global__ __launch_bounds__(256) void fused_projA_kernel(
    // proj args
    const float* __restrict__ mean, const float* __restrict__ var,
    const float* __restrict__ bm,   const float* __restrict__ bv,
    const ushort_t* __restrict__ wfm, const ushort_t* __restrict__ wfv,
    ushort_t* __restrict__ mv,
    // bucketA args
    const int* __restrict__ src, const int* __restrict__ dst,
    const float* __restrict__ w0, const float* __restrict__ w1,
    int* __restrict__ gcur, uint2* __restrict__ slots, int E, int nA)
{
    if ((int)blockIdx.x < nA) {
        // ------------------- bucketA role -------------------
        __shared__ uint2 s_rec[EPB];
        __shared__ int   s_gpos[EPB];
        __shared__ int   s_hist[256];
        __shared__ int   s_scn[256];
        __shared__ int   s_cur[256];
        __shared__ int   s_base[256];

        const int t  = threadIdx.x;
        const int e0 = blockIdx.x * EPB;
        const int n  = min(EPB, E - e0);

        s_hist[t] = 0;
        __syncthreads();

        int   myb[16];
        uint2 myr[16];
#pragma unroll
        for (int j = 0; j < 16; ++j) {
            const int e = e0 + t + j * 256;
            if (e < E) {
                const int d = dst[e];
                const int b = d >> 8;
                myb[j] = b;
                myr[j].x = (unsigned)src[e] | ((unsigned)(d & 255) << 16);
                myr[j].y = (unsigned)f2bf(w0[e]) | ((unsigned)f2bf(w1[e]) << 16);
                atomicAdd(&s_hist[b], 1);
            } else myb[j] = -1;
        }
        __syncthreads();

        if (t < NBKT) {
            const int c = s_hist[t];
            s_base[t] = t * SLOT_CAP + (c ? atomicAdd(&gcur[t], c) : 0);
        }
        const int x = s_hist[t];
        s_scn[t] = x;
        __syncthreads();
        for (int off = 1; off < 256; off <<= 1) {
            const int v = (t >= off) ? s_scn[t - off] : 0;
            __syncthreads();
            s_scn[t] += v;
            __syncthreads();
        }
        const int excl = s_scn[t] - x;
        __syncthreads();
        s_scn[t] = excl;
        s_cur[t] = 0;
        __syncthreads();

#pragma unroll
        for (int j = 0; j < 16; ++j) {
            if (myb[j] >= 0) {
                const int r = atomicAdd(&s_cur[myb[j]], 1);
                const int p = s_scn[myb[j]] + r;
                s_rec[p]  = myr[j];
                s_gpos[p] = s_base[myb[j]] + r;
            }
        }
        __syncthreads();

        for (int i = t; i < n; i += 256)
            slots[s_gpos[i]] = s_rec[i];
        return;
    }

    // ------------------- proj role -------------------
    const int wave = ((int)blockIdx.x - nA) * 4 + (threadIdx.x >> 6);
    if (wave >= N_WAVES) return;
    const int lane = threadIdx.x & 63;
    const int row0 = wave * 16;
    const int kq   = lane >> 4;             // 0..3
    const int arow = row0 + (lane & 15);

    f32x4 accm[8], accv[8];
#pragma unroll
    for (int ct = 0; ct < 8; ++ct) {
        accm[ct] = (f32x4){0.f, 0.f, 0.f, 0.f};
        accv[ct] = (f32x4){0.f, 0.f, 0.f, 0.f};
    }

    const float* mrow = mean + (size_t)arow * DIN;
    const float* vrow = var  + (size_t)arow * DIN;

#pragma unroll
    for (int kk = 0; kk < 4; ++kk) {
        const int kb = kk * 32 + kq * 8;
        const float4 am0 = *(const float4*)(mrow + kb);
        const float4 am1 = *(const float4*)(mrow + kb + 4);
        const float4 av0 = *(const float4*)(vrow + kb);
        const float4 av1 = *(const float4*)(vrow + kb + 4);
        bf16x8 a_m, a_v;
        a_m[0]=f2bf(am0.x); a_m[1]=f2bf(am0.y); a_m[2]=f2bf(am0.z); a_m[3]=f2bf(am0.w);
        a_m[4]=f2bf(am1.x); a_m[5]=f2bf(am1.y); a_m[6]=f2bf(am1.z); a_m[7]=f2bf(am1.w);
        a_v[0]=f2bf(av0.x); a_v[1]=f2bf(av0.y); a_v[2]=f2bf(av0.z); a_v[3]=f2bf(av0.w);
        a_v[4]=f2bf(av1.x); a_v[5]=f2bf(av1.y); a_v[6]=f2bf(av1.z); a_v[7]=f2bf(av1.w);

#pragma unroll
        for (int ct = 0; ct < 8; ++ct) {
            const bf16x8 b_m = *(const bf16x8*)(wfm + ((size_t)(ct * 4 + kk) * 64 + lane) * 8);
            const bf16x8 b_v = *(const bf16x8*)(wfv + ((size_t)(ct * 4 + kk) * 64 + lane) * 8);
            accm[ct] = __builtin_amdgcn_mfma_f32_16x16x32_bf16(a_m, b_m, accm[ct], 0, 0, 0);
            accv[ct] = __builtin_amdgcn_mfma_f32_16x16x32_bf16(a_v, b_v, accv[ct], 0, 0, 0);
        }
    }

#pragma unroll
    for (int ct = 0; ct < 8; ++ct) {
        const int col = ct * 16 + (lane & 15);
        const float bmc = bm[col];
        const float bvc = bv[col];
        const int pbase = (col >> 1) * 4 + (col & 1);   // pair-interleave offset
#pragma unroll
        for (int r = 0; r < 4; ++r) {
            const int row = row0 + kq * 4 + r;
            float m = accm[ct][r] + bmc;
            m = (m > 0.0f) ? m : (expf(m) - 1.0f);           // ELU
            float v = accv[ct][r] + bvc;
            v = ((v > 0.0f) ? v : 0.0f) + EPS_;              // ReLU + eps
            const float att = expf(-v);
            ushort_t* rowp = mv + (size_t)row * 256;
            rowp[pbase]     = f2bf(m * att);
            rowp[pbase + 2] = f2bf(v * att * att);
        }
    }
}

// ---------------------------------------------------------------------------
// Kernel 2 (phase B): fine counting sort per bucket — TWO-PASS over slots
// (L2-hot) instead of register staging, which forced scratch spill (dynamic
// index into reg array). Pass 1: histogram. Pass 2: re-read + place.
// ---------------------------------------------------------------------------
__global__ __launch_bounds__(256) void bucketB_kernel(
    const int* __restrict__ gcur,
    const uint2* __restrict__ slots, uint2* __restrict__ final_e,
    int* __restrict__ node_start)
{
    __shared__ int s_hist[256];
    __shared__ int s_scn[256];
    __shared__ int s_cur[256];
    __shared__ int s_red[256];

    const int b = blockIdx.x;
    const int t = threadIdx.x;

    // base = sum gcur[0..b)
    s_red[t]  = (t < b) ? gcur[t] : 0;
    s_hist[t] = 0;
    __syncthreads();
    for (int off = 128; off > 0; off >>= 1) {
        if (t < off) s_red[t] += s_red[t + off];
        __syncthreads();
    }
    const int base = s_red[0];
    const int cnt  = gcur[b];
    const uint2* slot = slots + (size_t)b * SLOT_CAP;

    // pass 1: histogram of fine key
    for (int i = t; i < cnt; i += 256)
        atomicAdd(&s_hist[(slot[i].x >> 16) & 255], 1);
    __syncthreads();

    // exclusive scan
    const int x = s_hist[t];
    s_scn[t] = x;
    __syncthreads();
    for (int off = 1; off < 256; off <<= 1) {
        const int v = (t >= off) ? s_scn[t - off] : 0;
        __syncthreads();
        s_scn[t] += v;
        __syncthreads();
    }
    const int excl = s_scn[t] - x;
    __syncthreads();

    const int gidx = b * 256 + t;
    if (gidx <= N_NODES) node_start[gidx] = base + excl;

    s_cur[t] = excl;
    __syncthreads();

    // pass 2: place records (slots re-read from L2)
    for (int i = t; i < cnt; i += 256) {
        const uint2 r = slot[i];
        const int f = (r.x >> 16) & 255;
        const int p = atomicAdd(&s_cur[f], 1);
        final_e[base + p] = r;
    }
}

// ---------------------------------------------------------------------------
// Kernel 3: gather aggregation — two edges per gather instruction (half-wave
// split), 16 B/lane dwordx4 from interleaved mv rows. At the vector-memory
// path roofline (~7.8 TB/s logical flow) — leave structure as-is.
// ---------------------------------------------------------------------------
#define PAIR_FMA(RW, G) do {                                                 \
    const float a0 = bflo(RW), a1 = bfhi(RW);                                \
    am0 = fmaf(a0, bflo((G).x), am0); am1 = fmaf(a0, bfhi((G).x), am1);      \
    av0 = fmaf(a1, bflo((G).y), av0); av1 = fmaf(a1, bfhi((G).y), av1);      \
    am2 = fmaf(a0, bflo((G).z), am2); am3 = fmaf(a0, bfhi((G).z), am3);      \
    av2 = fmaf(a1, bflo((G).w), av2); av3 = fmaf(a1, bfhi((G).w), av3);      \
} while (0)

__global__ __launch_bounds__(256) void agg_kernel(
    const ushort_t* __restrict__ mv,
    const uint2* __restrict__ edges, const int* __restrict__ node_start,
    float* __restrict__ out_m, float* __restrict__ out_v)
{
    const int node = blockIdx.x * 4 + (threadIdx.x >> 6);
    const int lane = threadIdx.x & 63;
    const int half = lane >> 5;
    const int l    = lane & 31;
    if (node >= N_NODES) return;

    const int j0 = node_start[node];
    const int j1 = node_start[node + 1];

    float am0=0.f, am1=0.f, am2=0.f, am3=0.f;
    float av0=0.f, av1=0.f, av2=0.f, av3=0.f;

    int j = j0;

    if ((j & 1) && j < j1) {
        const uint2 r = edges[j];
        const unsigned rw = half ? 0u : r.y;
        const uint4 g = *(const uint4*)(mv + (size_t)(r.x & 0xffffu) * 256 + l * 8);
        PAIR_FMA(rw, g);
        ++j;
    }

    for (; j + 8 <= j1; j += 8) {
        const uint4 e0 = *(const uint4*)(edges + j + 0);
        const uint4 e1 = *(const uint4*)(edges + j + 2);
        const uint4 e2 = *(const uint4*)(edges + j + 4);
        const uint4 e3 = *(const uint4*)(edges + j + 6);
        const unsigned s0 = half ? e0.z : e0.x, w0 = half ? e0.w : e0.y;
        const unsigned s1 = half ? e1.z : e1.x, w1 = half ? e1.w : e1.y;
        const unsigned s2 = half ? e2.z : e2.x, w2 = half ? e2.w : e2.y;
        const unsigned s3 = half ? e3.z : e3.x, w3 = half ? e3.w : e3.y;
        const uint4 g0 = *(const uint4*)(mv + (size_t)(s0 & 0xffffu) * 256 + l * 8);
        const uint4 g1 = *(const uint4*)(mv + (size_t)(s1 & 0xffffu) * 256 + l * 8);
        const uint4 g2 = *(const uint4*)(mv + (size_t)(s2 & 0xffffu) * 256 + l * 8);
        const uint4 g3 = *(const uint4*)(mv + (size_t)(s3 & 0xffffu) * 256 + l * 8);
        PAIR_FMA(w0, g0);
        PAIR_FMA(w1, g1);
        PAIR_FMA(w2, g2);
        PAIR_FMA(w3, g3);
    }

    for (; j + 2 <= j1; j += 2) {
        const uint4 e = *(const uint4*)(edges + j);
        const unsigned s = half ? e.z : e.x, w = half ? e.w : e.y;
        const uint4 g = *(const uint4*)(mv + (size_t)(s & 0xffffu) * 256 + l * 8);
        PAIR_FMA(w, g);
    }

    if (j < j1) {
        const uint2 r = edges[j];
        const unsigned rw = half ? 0u : r.y;
        const uint4 g = *(const uint4*)(mv + (size_t)(r.x & 0xffffu) * 256 + l * 8);
        PAIR_FMA(rw, g);
    }

    am0 += __shfl_xor(am0, 32); am1 += __shfl_xor(am1, 32);
    am2 += __shfl_xor(am2, 32); am3 += __shfl_xor(am3, 32);
    av0 += __shfl_xor(av0, 32); av1 += __shfl_xor(av1, 32);
    av2 += __shfl_xor(av2, 32); av3 += __shfl_xor(av3, 32);

    if (half == 0) {
        *(float4*)(out_m + (size_t)node * DOUT + l * 4) = make_float4(am0, am1, am2, am3);
        *(float4*)(out_v + (size_t)node * DOUT + l * 4) = make_float4(av0, av1, av2, av3);
    }
}

// ---------------------------------------------------------------------------
extern "C" void kernel_launch(void* const* d_in, const int* in_sizes, int n_in,
                              void* d_out, int out_size, void* d_ws, size_t ws_size,
                              hipStream_t stream) {
    const float* mean = (const float*)d_in[0];
    const float* var  = (const float*)d_in[1];
    const float* Wm   = (const float*)d_in[2];
    const float* bm   = (const float*)d_in[3];
    const float* Wv   = (const float*)d_in[4];
    const float* bv   = (const float*)d_in[5];
    const float* a0   = (const float*)d_in[6];
    const float* a1   = (const float*)d_in[7];
    const int*   es   = (const int*)d_in[8];
    const int*   ed   = (const int*)d_in[9];
    const int    E    = in_sizes[6];

    // Workspace layout (byte offsets, 16B-aligned):
    //   mv [N][256] bf16           0          .. 25,600,000
    //   slots uint2[196*5120]      25,600,000 .. 33,628,160
    //   final_e uint2[E]           33,628,160 .. 40,028,160
    //   node_start int[N+1]        40,028,160 .. 40,228,164
    //   gcur int[196]              40,228,176 .. 40,228,960
    //   wfm/wfv bf16 frags         40,228,976 .. 40,294,512
    char* ws = (char*)d_ws;
    ushort_t* mv        = (ushort_t*)ws;
    uint2* slots        = (uint2*)(ws + 25600000);
    uint2* final_e      = (uint2*)(ws + 33628160);
    int*   node_start   = (int*)  (ws + 40028160);
    int*   gcur         = (int*)  (ws + 40228176);
    ushort_t* wfm       = (ushort_t*)(ws + 40228976);
    ushort_t* wfv       = wfm + 16384;

    float* out_m = (float*)d_out;
    float* out_v = out_m + (size_t)N_NODES * DOUT;

    prep_w_kernel<<<64, 256, 0, stream>>>(Wm, Wv, wfm, wfv, gcur);

    const int nA = (E + EPB - 1) / EPB;
    fused_projA_kernel<<<nA + NB_PROJ, 256, 0, stream>>>(
        mean, var, bm, bv, wfm, wfv, mv,
        es, ed, a0, a1, gcur, slots, E, nA);

    bucketB_kernel<<<NBKT, 256, 0, stream>>>(
        gcur, slots, final_e, node_start);

    agg_kernel<<<(N_NODES + 3) / 4, 256, 0, stream>>>(
        mv, final_e, node_start, out_m, out_v);
}